// Round 17
// baseline (1176.040 us; speedup 1.0000x reference)
//
#include <hip/hip_runtime.h>
#include <stdint.h>

typedef unsigned short u16;
typedef __attribute__((ext_vector_type(8))) short short8;
typedef __attribute__((ext_vector_type(4))) float f32x4;

#define RSQC 0.9999950000374997f  // 1/sqrt(1+1e-5)
#define OUT_ELEMS 12582912        // 4*768*64*64 (f32 elements)

__device__ __forceinline__ float bf2f(u16 u) {
  union { uint32_t i; float f; } v; v.i = ((uint32_t)u) << 16; return v.f;
}
__device__ __forceinline__ u16 f2bf(float f) {
  union { uint32_t i; float f; } v; v.f = f;
  uint32_t i = v.i;
  i += 0x7fffu + ((i >> 16) & 1u);   // RTNE (finite inputs)
  return (u16)(i >> 16);
}
// async global->LDS, 16B/lane; LDS dest = wave-uniform base + lane*16 (HW rule)
__device__ __forceinline__ void gload16(const u16* g, u16* l) {
  __builtin_amdgcn_global_load_lds(
      (const __attribute__((address_space(1))) uint32_t*)g,
      (__attribute__((address_space(3))) uint32_t*)l, 16, 0, 0);
}

// ---------------- diagnostics ----------------
__global__ __launch_bounds__(256) void probe_fill(float* out, float val) {
  for (size_t i = (size_t)blockIdx.x * 256 + threadIdx.x; i < OUT_ELEMS; i += (size_t)gridDim.x * 256)
    out[i] = val;
}

// ---------------- small kernels (f32 inputs) ----------------

__global__ __launch_bounds__(64) void sim_argmax(const float* __restrict__ text,
                                                 const float* __restrict__ tmem,
                                                 int* __restrict__ idx) {
  const int i = blockIdx.x, lane = threadIdx.x;
  const float* t = text + (size_t)i * 768;
  float tr[12];
  float nt = 0.f;
#pragma unroll
  for (int k = 0; k < 12; ++k) { tr[k] = t[lane + k * 64]; nt += tr[k] * tr[k]; }
#pragma unroll
  for (int m = 32; m; m >>= 1) nt += __shfl_xor(nt, m);
  nt = sqrtf(nt);
  float best = -1e30f; int bj = 0;
  for (int j = 0; j < 171; ++j) {
    const float* tc = tmem + (size_t)j * 768;
    float dot = 0.f, nc = 0.f;
#pragma unroll
    for (int k = 0; k < 12; ++k) {
      float y = tc[lane + k * 64];
      dot += tr[k] * y;
      nc += y * y;
    }
#pragma unroll
    for (int m = 32; m; m >>= 1) {
      dot += __shfl_xor(dot, m);
      nc += __shfl_xor(nc, m);
    }
    float s = dot / fmaxf(nt * sqrtf(nc), 1e-8f);
    if (s > best) { best = s; bj = j; }  // strict > keeps first max (ref semantics)
  }
  if (lane == 0) idx[i] = bj;
}

// D[j][c] (256 x 768) bf16 = memory[idx[j]][c], rows >=200 zero
__global__ __launch_bounds__(256) void build_d(const float* __restrict__ memory,
                                               const int* __restrict__ idx,
                                               u16* __restrict__ D) {
  int i = blockIdx.x * 256 + threadIdx.x;  // 256*768
  if (i >= 256 * 768) return;
  int c = i % 768, j = i / 768;
  u16 v = 0;
  if (j < 200) {
    int ii = idx[j];
    ii = ii < 0 ? 0 : (ii > 170 ? 170 : ii);
    v = f2bf(memory[(size_t)ii * 768 + c]);
  }
  D[i] = v;
}

// per-position softmax over 200 classes; 256 blocks x 64 pos, 4 class-quarters/pos.
__global__ __launch_bounds__(256) void wcls_kernel(const float* __restrict__ preds,
                                                   u16* __restrict__ wcls) {
  __shared__ float red[4][64];
  const int tid = threadIdx.x;
  const int p = tid & 63, q = tid >> 6;
  const int pos = blockIdx.x * 64 + p;
  const int b = pos >> 12, hw = pos & 4095;
  const float* pp = preds + (size_t)b * 200 * 4096 + hw;
  const int nlo = q * 50, nhi = nlo + 50;
  float mx = -1e30f;
  for (int n = nlo; n < nhi; ++n) mx = fmaxf(mx, pp[(size_t)n * 4096]);
  red[q][p] = mx;
  __syncthreads();
  const float m = fmaxf(fmaxf(red[0][p], red[1][p]), fmaxf(red[2][p], red[3][p]));
  __syncthreads();
  float s = 0.f;
  for (int n = nlo; n < nhi; ++n) s += __expf(pp[(size_t)n * 4096] - m);
  red[q][p] = s;
  __syncthreads();
  const float inv = 1.f / (red[0][p] + red[1][p] + red[2][p] + red[3][p]);
  u16* w = wcls + (size_t)pos * 256;
#pragma unroll
  for (int c8 = 0; c8 < 8; ++c8) {
    short8 v;
    const int base = q * 64 + c8 * 8;
#pragma unroll
    for (int j = 0; j < 8; ++j) {
      const int n = base + j;
      float e = (n < 200) ? __expf(pp[(size_t)n * 4096] - m) * inv : 0.f;
      v[j] = (short)f2bf(e);
    }
    *(short8*)&w[base] = v;
  }
}

// feats f32 (B,768,4096) -> featsT bf16 (B*4096, 768)
__global__ __launch_bounds__(256) void transpose_feats(const float* __restrict__ feats,
                                                       u16* __restrict__ ft) {
  __shared__ u16 t[64][65];
  const int bz = blockIdx.z, c0 = blockIdx.y * 64, p0 = blockIdx.x * 64;
  const int col = threadIdx.x & 63, row4 = threadIdx.x >> 6;
  const float* src = feats + ((size_t)bz * 768 + c0) * 4096 + p0;
#pragma unroll
  for (int i = 0; i < 16; ++i) {
    int ci = i * 4 + row4;
    t[ci][col] = f2bf(src[(size_t)ci * 4096 + col]);
  }
  __syncthreads();
  u16* dst = ft + ((size_t)bz * 4096 + p0) * 768 + c0;
#pragma unroll
  for (int i = 0; i < 16; ++i) {
    int pi = i * 4 + row4;
    dst[(size_t)pi * 768 + col] = t[col][pi];
  }
}

// fused f32->bf16 cast of the six attention weight matrices
__global__ __launch_bounds__(256) void cast_all(
    const float* __restrict__ s0, u16* __restrict__ d0,
    const float* __restrict__ s1, u16* __restrict__ d1,
    const float* __restrict__ s2, u16* __restrict__ d2,
    const float* __restrict__ s3, u16* __restrict__ d3,
    const float* __restrict__ s4, u16* __restrict__ d4,
    const float* __restrict__ s5, u16* __restrict__ d5) {
  int i = blockIdx.x * 256 + threadIdx.x;  // < 917504
  if (i < 196608) d0[i] = f2bf(s0[i]);
  else if (i < 393216) d1[i - 196608] = f2bf(s1[i - 196608]);
  else if (i < 589824) d2[i - 393216] = f2bf(s2[i - 393216]);
  else if (i < 786432) d3[i - 589824] = f2bf(s3[i - 589824]);
  else if (i < 851968) d4[i - 786432] = f2bf(s4[i - 786432]);
  else if (i < 917504) d5[i - 851968] = f2bf(s5[i - 851968]);
}

// Coalesced fragment repack: lane owns (o, c-oct), reads 288 contiguous bytes
// (8 c x 9 taps f32), writes 9 tap-fragments as wave-contiguous 1KB stores.
__global__ __launch_bounds__(256) void repack2(const float* __restrict__ bw,
                                               u16* __restrict__ w9f, int c_base) {
  const int gid = blockIdx.x * 4 + (threadIdx.x >> 6);  // 0..1151
  const int lane = threadIdx.x & 63;
  const int mfrag = gid % 48, kc = gid / 48;
  const int o = mfrag * 16 + (lane & 15);
  const int c = c_base + kc * 32 + (lane >> 4) * 8;
  const float* src = bw + ((size_t)o * 1536 + c) * 9;
  float v[72];
#pragma unroll
  for (int t = 0; t < 72; ++t) v[t] = src[t];
#pragma unroll
  for (int tap = 0; tap < 9; ++tap) {
    short8 w;
#pragma unroll
    for (int j = 0; j < 8; ++j) w[j] = (short)f2bf(v[j * 9 + tap]);
    *(short8*)&w9f[(((size_t)(kc * 9 + tap) * 48 + mfrag) << 9) + lane * 8] = w;
  }
}

// ---------------- 128x128 MFMA GEMM, double-buffered + bank-swizzled LDS ----
template <bool EP>
__global__ __launch_bounds__(256) void gemm_std(
    const u16* __restrict__ A, const u16* __restrict__ Bt, u16* __restrict__ out,
    const float* __restrict__ g, const float* __restrict__ bia,
    int N, int K, int lda, int ldb) {
  __shared__ __attribute__((aligned(16))) u16 As[2][128 * 32];
  __shared__ __attribute__((aligned(16))) u16 Bs[2][128 * 32];
  const int tid = threadIdx.x, lane = tid & 63, wv = tid >> 6;
  const int wr = wv >> 1, wc = wv & 1;
  const int m0 = blockIdx.y * 128, n0 = blockIdx.x * 128;
  const int r0 = lane >> 2, ksl = (lane & 3) * 8;
  const int wofs = (lane >> 2) * 32 + (((lane & 3) ^ ((lane >> 3) & 3)) << 3);
  const int rsl = (((lane >> 4) ^ ((lane >> 1) & 3)) << 3);
  f32x4 acc[4][4] = {};
  const int nt = K >> 5;

  short8 a0[2], b0[2], a1[2], b1[2];
  auto LOAD = [&](int t, short8 av[2], short8 bv[2]) {
    const int k0 = t << 5;
#pragma unroll
    for (int i = 0; i < 2; ++i) {
      const int row = (wv * 2 + i) * 16 + r0;
      av[i] = *(const short8*)(A + (size_t)(m0 + row) * lda + k0 + ksl);
      bv[i] = *(const short8*)(Bt + (size_t)(n0 + row) * ldb + k0 + ksl);
    }
  };
  auto STORE = [&](int buf, short8 av[2], short8 bv[2]) {
#pragma unroll
    for (int i = 0; i < 2; ++i) {
      const int o = (wv * 2 + i) * 512 + wofs;
      *(short8*)&As[buf][o] = av[i];
      *(short8*)&Bs[buf][o] = bv[i];
    }
  };
  auto COMPUTE = [&](int buf) {
    short8 a[4], b[4];
#pragma unroll
    for (int mi = 0; mi < 4; ++mi)
      a[mi] = *(const short8*)&As[buf][(wr * 4 + mi) * 512 + (lane & 15) * 32 + rsl];
#pragma unroll
    for (int ni = 0; ni < 4; ++ni)
      b[ni] = *(const short8*)&Bs[buf][(wc * 4 + ni) * 512 + (lane & 15) * 32 + rsl];
#pragma unroll
    for (int mi = 0; mi < 4; ++mi)
#pragma unroll
      for (int ni = 0; ni < 4; ++ni)
        acc[mi][ni] = __builtin_amdgcn_mfma_f32_16x16x32_bf16(a[mi], b[ni], acc[mi][ni], 0, 0, 0);
  };

  LOAD(0, a0, b0);
  for (int t = 0; t < nt; t += 2) {
    STORE(0, a0, b0);
    __syncthreads();
    LOAD(t + 1, a1, b1);
    COMPUTE(0);
    STORE(1, a1, b1);
    __syncthreads();
    if (t + 2 < nt) LOAD(t + 2, a0, b0);
    COMPUTE(1);
  }
  const int mb = m0 + wr * 64 + ((lane >> 4) << 2);
  const int nb = n0 + wc * 64 + (lane & 15);
#pragma unroll
  for (int ni = 0; ni < 4; ++ni) {
    const int n = nb + ni * 16;
    float s = 1.f, bb_ = 0.f;
    if (EP) { s = g[n] * RSQC; bb_ = bia[n]; }
#pragma unroll
    for (int mi = 0; mi < 4; ++mi)
#pragma unroll
      for (int r = 0; r < 4; ++r) {
        float v = acc[mi][ni][r];
        if (EP) v = fmaxf(v * s + bb_, 0.f);
        out[(size_t)(mb + mi * 16 + r) * N + n] = f2bf(v);
      }
  }
}

// Swapped GEMM (vT path): out bf16 (b, m, pos); BN per-m.
__global__ __launch_bounds__(256) void gemm_swv(
    const u16* __restrict__ A, const u16* __restrict__ Bt, u16* __restrict__ out,
    const float* __restrict__ g, const float* __restrict__ bia,
    int Mtot, int K, int lda, int ldb) {
  __shared__ __attribute__((aligned(16))) u16 As[2][128 * 32];
  __shared__ __attribute__((aligned(16))) u16 Bs[2][128 * 32];
  const int tid = threadIdx.x, lane = tid & 63, wv = tid >> 6;
  const int wr = wv >> 1, wc = wv & 1;
  const int m0 = blockIdx.y * 128, n0 = blockIdx.x * 128;
  const int r0 = lane >> 2, ksl = (lane & 3) * 8;
  const int wofs = (lane >> 2) * 32 + (((lane & 3) ^ ((lane >> 3) & 3)) << 3);
  const int rsl = (((lane >> 4) ^ ((lane >> 1) & 3)) << 3);
  f32x4 acc[4][4] = {};
  const int nt = K >> 5;

  short8 a0[2], b0[2], a1[2], b1[2];
  auto LOAD = [&](int t, short8 av[2], short8 bv[2]) {
    const int k0 = t << 5;
#pragma unroll
    for (int i = 0; i < 2; ++i) {
      const int row = (wv * 2 + i) * 16 + r0;
      av[i] = *(const short8*)(A + (size_t)(m0 + row) * lda + k0 + ksl);
      bv[i] = *(const short8*)(Bt + (size_t)(n0 + row) * ldb + k0 + ksl);
    }
  };
  auto STORE = [&](int buf, short8 av[2], short8 bv[2]) {
#pragma unroll
    for (int i = 0; i < 2; ++i) {
      const int o = (wv * 2 + i) * 512 + wofs;
      *(short8*)&As[buf][o] = av[i];
      *(short8*)&Bs[buf][o] = bv[i];
    }
  };
  auto COMPUTE = [&](int buf) {
    short8 a[4], b[4];
#pragma unroll
    for (int mi = 0; mi < 4; ++mi)
      a[mi] = *(const short8*)&As[buf][(wr * 4 + mi) * 512 + (lane & 15) * 32 + rsl];
#pragma unroll
    for (int ni = 0; ni < 4; ++ni)
      b[ni] = *(const short8*)&Bs[buf][(wc * 4 + ni) * 512 + (lane & 15) * 32 + rsl];
#pragma unroll
    for (int mi = 0; mi < 4; ++mi)
#pragma unroll
      for (int ni = 0; ni < 4; ++ni)
        acc[mi][ni] = __builtin_amdgcn_mfma_f32_16x16x32_bf16(a[mi], b[ni], acc[mi][ni], 0, 0, 0);
  };

  LOAD(0, a0, b0);
  for (int t = 0; t < nt; t += 2) {
    STORE(0, a0, b0);
    __syncthreads();
    LOAD(t + 1, a1, b1);
    COMPUTE(0);
    STORE(1, a1, b1);
    __syncthreads();
    if (t + 2 < nt) LOAD(t + 2, a0, b0);
    COMPUTE(1);
  }
  const int mb = m0 + wr * 64 + ((lane >> 4) << 2);
  const int nb = n0 + wc * 64 + (lane & 15);
#pragma unroll
  for (int mi = 0; mi < 4; ++mi)
#pragma unroll
    for (int r = 0; r < 4; ++r) {
      const int m = mb + mi * 16 + r;
      const float s = g[m] * RSQC, bb_ = bia[m];
#pragma unroll
      for (int ni = 0; ni < 4; ++ni) {
        const int n = nb + ni * 16;
        out[((size_t)(n >> 12) * Mtot + m) * 4096 + (n & 4095)] =
            f2bf(fmaxf(acc[mi][ni][r] * s + bb_, 0.f));
      }
    }
}

// ---------------- implicit 3x3 conv, 128-row blocks (R15-proven) ----------------
// MODE 1: store raw f32; MODE 2: in-place +BN+relu.
template <int MODE>
__global__ __launch_bounds__(256) void conv_frag(
    const u16* __restrict__ Af, const u16* __restrict__ X, float* out,
    const float* __restrict__ g, const float* __restrict__ bia) {
  __shared__ __attribute__((aligned(16))) u16 Hb[2][264 * 32];
  const int tid = threadIdx.x, lane = tid & 63, wv = tid >> 6;
  const int wr = wv >> 1, wc = wv & 1;
  const int id = blockIdx.y * 128 + blockIdx.x;
  const int xcd = id & 7, sl = id >> 3;
  const int m0 = (sl % 6) * 128;
  const int n0 = (xcd * 16 + sl / 6) * 128;
  f32x4 acc[4][4] = {};

  int vmask[4];
#pragma unroll
  for (int i = 0; i < 4; ++i) {
    const int hw = (n0 + wc * 64 + i * 16 + (lane & 15)) & 4095;
    const int h = hw >> 6, w = hw & 63;
    int m = 0;
#pragma unroll
    for (int t = 0; t < 9; ++t)
      if ((unsigned)(h + t / 3 - 1) < 64u && (unsigned)(w + t % 3 - 1) < 64u) m |= 1 << t;
    vmask[i] = m;
  }

  const int fb = (m0 >> 4) + wr * 4;
  auto aload = [&](int kc, int tap, short8 d[4]) {
    const u16* base = Af + ((size_t)((kc * 9 + tap) * 48 + fb) << 9) + lane * 8;
#pragma unroll
    for (int mi = 0; mi < 4; ++mi) d[mi] = *(const short8*)(base + (mi << 9));
  };
  auto hstage = [&](int kc, int buf) {
#pragma unroll
    for (int j = 0; j < 5; ++j) {
      const int cid = tid + j * 256;
      if (cid < 1032) {
        int q = n0 - 65 + (cid >> 2);
        q = q < 0 ? 0 : (q > 16383 ? 16383 : q);  // clamped rows only used masked
        const int row = cid >> 2;
        const int s = (cid & 3) ^ ((row >> 1) & 3);
        gload16(X + (size_t)q * 768 + kc * 32 + s * 8, &Hb[buf][(size_t)cid * 8]);
      }
    }
  };

  hstage(0, 0);
  short8 acur[4], anxt[4];
  aload(0, 0, acur);
  __syncthreads();
  int p = 0;
  for (int kc = 0; kc < 24; ++kc) {
    if (kc < 23) hstage(kc + 1, p ^ 1);
#pragma unroll
    for (int tap = 0; tap < 9; ++tap) {
      const int nk = (tap == 8) ? (kc == 23 ? 23 : kc + 1) : kc;
      const int ntp = (tap == 8) ? 0 : tap + 1;
      aload(nk, ntp, anxt);
      const int shift = (tap / 3 - 1) * 64 + (tap % 3 - 1);
#pragma unroll
      for (int ni = 0; ni < 4; ++ni) {
        const int hrow = wc * 64 + ni * 16 + (lane & 15) + 65 + shift;
        short8 bv = *(const short8*)((const char*)&Hb[p][0] + hrow * 64 +
                                     (((lane >> 4) ^ ((hrow >> 1) & 3)) << 4));
        short8 z = {};
        if (!((vmask[ni] >> tap) & 1)) bv = z;
#pragma unroll
        for (int mi = 0; mi < 4; ++mi)
          acc[mi][ni] = __builtin_amdgcn_mfma_f32_16x16x32_bf16(acur[mi], bv, acc[mi][ni], 0, 0, 0);
      }
#pragma unroll
      for (int mi = 0; mi < 4; ++mi) acur[mi] = anxt[mi];
    }
    if (kc < 23) {
      __syncthreads();
      p ^= 1;
    }
  }
  const int mb = m0 + wr * 64 + ((lane >> 4) << 2);
  const int nb = n0 + wc * 64 + (lane & 15);
#pragma unroll
  for (int mi = 0; mi < 4; ++mi)
#pragma unroll
    for (int r = 0; r < 4; ++r) {
      const int m = mb + mi * 16 + r;
      float s = 0.f, bb_ = 0.f;
      if (MODE == 2) { s = g[m] * RSQC; bb_ = bia[m]; }
#pragma unroll
      for (int ni = 0; ni < 4; ++ni) {
        const int n = nb + ni * 16;
        const size_t oidx = ((size_t)(n >> 12) * 768 + m) * 4096 + (n & 4095);
        if (MODE == 1) out[oidx] = acc[mi][ni][r];
        else out[oidx] = fmaxf((acc[mi][ni][r] + out[oidx]) * s + bb_, 0.f);
      }
    }
}

// ---------------- A/B variant: 64-row m-tiles, 1536 blocks (4 blocks/CU) ----
// In-place +BN+relu epilogue (conv pass 2 only).
__global__ __launch_bounds__(256) void conv_ms(
    const u16* __restrict__ Af, const u16* __restrict__ X, float* out,
    const float* __restrict__ g, const float* __restrict__ bia) {
  __shared__ __attribute__((aligned(16))) u16 Hb[2][264 * 32];
  const int tid = threadIdx.x, lane = tid & 63, wv = tid >> 6;
  const int wr = wv >> 1, wc = wv & 1;
  const int id = blockIdx.x;
  const int xcd = id & 7, sl = id >> 3;  // sl 0..191
  const int m0 = (sl % 12) * 64;
  const int n0 = (xcd * 16 + sl / 12) * 128;
  f32x4 acc[2][4] = {};

  int vmask[4];
#pragma unroll
  for (int i = 0; i < 4; ++i) {
    const int hw = (n0 + wc * 64 + i * 16 + (lane & 15)) & 4095;
    const int h = hw >> 6, w = hw & 63;
    int m = 0;
#pragma unroll
    for (int t = 0; t < 9; ++t)
      if ((unsigned)(h + t / 3 - 1) < 64u && (unsigned)(w + t % 3 - 1) < 64u) m |= 1 << t;
    vmask[i] = m;
  }

  const int fb = (m0 >> 4) + wr * 2;
  auto aload = [&](int kc, int tap, short8 d[2]) {
    const u16* base = Af + ((size_t)((kc * 9 + tap) * 48 + fb) << 9) + lane * 8;
#pragma unroll
    for (int mi = 0; mi < 2; ++mi) d[mi] = *(const short8*)(base + (mi << 9));
  };
  auto hstage = [&](int kc, int buf) {
#pragma unroll
    for (int j = 0; j < 5; ++j) {
      const int cid = tid + j * 256;
      if (cid < 1032) {
        int q = n0 - 65 + (cid >> 2);
        q = q < 0 ? 0 : (q > 16383 ? 16383 : q);
        const int row = cid >> 2;
        const int s = (cid & 3) ^ ((row >> 1) & 3);
        gload16(X + (size_t)q * 768 + kc * 32 + s * 8, &Hb[buf][(size_t)cid * 8]);
      }
    }
  };

  hstage(0, 0);
  short8 acur[2], anxt[2];
  aload(0, 0, acur);
  __syncthreads();
  int p = 0;
  for (int kc = 0; kc < 24; ++kc) {
    if (kc < 23) hstage(kc + 1, p ^ 1);
#pragma unroll
    for (int tap = 0; tap < 9; ++tap) {
      const int nk = (tap == 8) ? (kc == 23 ? 23 : kc + 1) : kc;
      const int ntp = (tap == 8) ? 0 : tap + 1;
      aload(nk, ntp, anxt);
      const int shift = (tap / 3 - 1) * 64 + (tap % 3 - 1);
#pragma unroll
      for (int ni = 0; ni < 4; ++ni) {
        const int hrow = wc * 64 + ni * 16 + (lane & 15) + 65 + shift;
        short8 bv = *(const short8*)((const char*)&Hb[p][0] + hrow * 64 +
                                     (((lane >> 4) ^ ((hrow >> 1) & 3)) << 4));
        short8 z = {};
        if (!((vmask[ni] >> tap) & 1)) bv = z;
#pragma unroll
        for (int mi = 0; mi < 2; ++mi)
          acc[mi][ni] = __builtin_amdgcn_mfma_f32_16x16x32_bf16(acur[mi], bv, acc[mi][ni], 0, 0, 0);
      }
#pragma unroll
      for (int mi = 0; mi < 2; ++mi) acur[mi] = anxt[mi];
    }
    if (kc < 23) {
      __syncthreads();
      p ^= 1;
    }
  }
  const int mb = m0 + wr * 32 + ((lane >> 4) << 2);
  const int nb = n0 + wc * 64 + (lane & 15);
#pragma unroll
  for (int mi = 0; mi < 2; ++mi)
#pragma unroll
    for (int r = 0; r < 4; ++r) {
      const int m = mb + mi * 16 + r;
      const float s = g[m] * RSQC, bb_ = bia[m];
#pragma unroll
      for (int ni = 0; ni < 4; ++ni) {
        const int n = nb + ni * 16;
        const size_t oidx = ((size_t)(n >> 12) * 768 + m) * 4096 + (n & 4095);
        out[oidx] = fmaxf((acc[mi][ni][r] + out[oidx]) * s + bb_, 0.f);
      }
    }
}

// ---------------- flash attention (R12 structure; VGPR capped for 4 blocks/CU) ----
__global__ __launch_bounds__(256, 4) void flash_attn(const u16* Q,
                                                     const u16* __restrict__ Kg,
                                                     const u16* __restrict__ Vt,
                                                     u16* ctx) {
  __shared__ __attribute__((aligned(16))) u16 KVs[64 * 256];
  __shared__ __attribute__((aligned(16))) u16 Ps[4096];
  const int tid = threadIdx.x, lane = tid & 63, wv = tid >> 6;
  const int b = blockIdx.y, q0 = blockIdx.x * 64;
  const u16* qb = Q + ((size_t)b * 4096 + q0) * 256;
  const u16* kb = Kg + (size_t)b * 4096 * 256;
  const u16* vb = Vt + (size_t)b * 256 * 4096;
  const float scale = 0.0625f;

  short8 qf[8];
  {
    const int arow = wv * 16 + (lane & 15);
    const u16* qrow = qb + (size_t)arow * 256 + (lane >> 4) * 8;
#pragma unroll
    for (int kk = 0; kk < 8; ++kk) qf[kk] = *(const short8*)(qrow + kk * 32);
  }
  float mreg[4] = {-1e30f, -1e30f, -1e30f, -1e30f};
  float lsum[4] = {0.f, 0.f, 0.f, 0.f};
  f32x4 o[16] = {};

  for (int t = 0; t < 64; ++t) {
    {
      const int r = tid >> 5, sb = (tid & 31) * 16;
      const char* ksrc = (const char*)(kb + (size_t)t * 64 * 256);
#pragma unroll
      for (int i = 0; i < 8; ++i) {
        int row = i * 8 + r;
        short8 v = *(const short8*)(ksrc + (size_t)row * 512 + sb);
        *(short8*)((char*)KVs + row * 512 + (sb ^ ((row & 7) << 4))) = v;
      }
    }
    __syncthreads();
    f32x4 s4[4] = {};
    __builtin_amdgcn_s_setprio(1);
#pragma unroll
    for (int kk = 0; kk < 8; ++kk) {
      const int cb = (kk * 32 + ((lane >> 4) * 8)) * 2;
#pragma unroll
      for (int ni = 0; ni < 4; ++ni) {
        const int brow = ni * 16 + (lane & 15);
        short8 bb = *(const short8*)((const char*)KVs + brow * 512 + (cb ^ ((brow & 7) << 4)));
        s4[ni] = __builtin_amdgcn_mfma_f32_16x16x32_bf16(qf[kk], bb, s4[ni], 0, 0, 0);
      }
    }
    __builtin_amdgcn_s_setprio(0);
    float al[4], p[4][4];
#pragma unroll
    for (int r = 0; r < 4; ++r) {
      float v0 = fmaxf(fmaxf(s4[0][r], s4[1][r]), fmaxf(s4[2][r], s4[3][r]));
      v0 = fmaxf(v0, __shfl_xor(v0, 1));
      v0 = fmaxf(v0, __shfl_xor(v0, 2));
      v0 = fmaxf(v0, __shfl_xor(v0, 4));
      v0 = fmaxf(v0, __shfl_xor(v0, 8));
      const float mn = fmaxf(mreg[r], v0 * scale);
      al[r] = __expf(mreg[r] - mn);
      mreg[r] = mn;
      float srow = 0.f;
#pragma unroll
      for (int ni = 0; ni < 4; ++ni) {
        float pv = __expf(s4[ni][r] * scale - mn);
        p[ni][r] = pv;
        srow += pv;
      }
      srow += __shfl_xor(srow, 1);
      srow += __shfl_xor(srow, 2);
      srow += __shfl_xor(srow, 4);
      srow += __shfl_xor(srow, 8);
      lsum[r] = lsum[r] * al[r] + srow;
    }
#pragma unroll
    for (int nf = 0; nf < 16; ++nf)
#pragma unroll
      for (int r = 0; r < 4; ++r) o[nf][r] *= al[r];
    {
      char* pbase = (char*)Ps + wv * 2048;
#pragma unroll
      for (int ni = 0; ni < 4; ++ni)
#pragma unroll
        for (int r = 0; r < 4; ++r) {
          const int row = ((lane >> 4) << 2) + r, col = ni * 16 + (lane & 15);
          *(u16*)(pbase + row * 128 + ((col * 2) ^ ((row & 7) << 4))) = f2bf(p[ni][r]);
        }
    }
    __syncthreads();
    {
      const int slot = tid & 7;
#pragma unroll
      for (int i = 0; i < 8; ++i) {
        const int cc = i * 32 + (tid >> 3);
        short8 v = *(const short8*)((const char*)vb + ((size_t)cc * 4096 + t * 64) * 2 + slot * 16);
        *(short8*)((char*)KVs + cc * 128 + ((slot * 16) ^ ((cc & 7) << 4))) = v;
      }
    }
    __syncthreads();
    short8 pa[2];
#pragma unroll
    for (int kk = 0; kk < 2; ++kk) {
      const int row = lane & 15;
      const int cb = (kk * 32 + ((lane >> 4) * 8)) * 2;
      pa[kk] = *(const short8*)((const char*)Ps + wv * 2048 + row * 128 + (cb ^ ((row & 7) << 4)));
    }
    __builtin_amdgcn_s_setprio(1);
#pragma unroll
    for (int nf = 0; nf < 16; ++nf) {
      const int crow = nf * 16 + (lane & 15);
#pragma unroll
      for (int kk = 0; kk < 2; ++kk) {
        const int kb2 = (kk * 32 + ((lane >> 4) * 8)) * 2;
        short8 bb = *(const short8*)((const char*)KVs + crow * 128 + (kb2 ^ ((crow & 7) << 4)));
        o[nf] = __builtin_amdgcn_mfma_f32_16x16x32_bf16(pa[kk], bb, o[nf], 0, 0, 0);
      }
    }
    __builtin_amdgcn_s_setprio(0);
    __syncthreads();
  }
  u16* cb_ = ctx + ((size_t)b * 4096 + q0) * 256;
#pragma unroll
  for (int r = 0; r < 4; ++r) {
    const int row = wv * 16 + ((lane >> 4) << 2) + r;
    const float inv = 1.f / lsum[r];
#pragma unroll
    for (int nf = 0; nf < 16; ++nf) {
      const int col = nf * 16 + (lane & 15);
      cb_[(size_t)row * 256 + col] = f2bf(o[nf][r] * inv);
    }
  }
}

// ---------------- launch ----------------

extern "C" void kernel_launch(void* const* d_in, const int* in_sizes, int n_in,
                              void* d_out, int out_size, void* d_ws, size_t ws_size,
                              hipStream_t stream) {
  (void)in_sizes; (void)n_in; (void)out_size;
  const float* feats  = (const float*)d_in[0];
  const float* preds  = (const float*)d_in[1];
  const float* text   = (const float*)d_in[2];
  const float* memory = (const float*)d_in[3];
  const float* tmem   = (const float*)d_in[4];
  const float* qw1 = (const float*)d_in[5];  const float* qg1 = (const float*)d_in[6];  const float* qb1 = (const float*)d_in[7];
  const float* qw2 = (const float*)d_in[8];  const float* qg2 = (const float*)d_in[9];  const float* qb2 = (const float*)d_in[10];
  const float* kw1 = (const float*)d_in[11]; const float* kg1 = (const float*)d_in[12]; const float* kb1 = (const float*)d_in[13];
  const float* kw2 = (const float*)d_in[14]; const float* kg2 = (const float*)d_in[15]; const float* kb2 = (const float*)d_in[16];
  const float* vw  = (const float*)d_in[17]; const float* vg  = (const float*)d_in[18]; const float* vb  = (const float*)d_in[19];
  const float* ow  = (const float*)d_in[20]; const float* og  = (const float*)d_in[21]; const float* ob  = (const float*)d_in[22];
  const float* bw  = (const float*)d_in[23]; const float* bg  = (const float*)d_in[24]; const float* bb  = (const float*)d_in[25];

  float* dout = (float*)d_out;  // 12,582,912 f32
  char* ws = (char*)d_ws;
  u16* featsT = (u16*)(ws);                           // 25,165,824 B
  u16* selout = (u16*)(ws + 25165824);                // 25,165,824 B
  u16* S2     = (u16*)(ws + 50331648);                //  8,388,608 B (k1 -> q1)
  u16* qw1c   = (u16*)(ws + 58720256);
  u16* kw1c   = (u16*)(ws + 59113472);
  u16* vwc    = (u16*)(ws + 59506688);
  u16* owc    = (u16*)(ws + 59899904);
  u16* qw2c   = (u16*)(ws + 60293120);
  u16* kw2c   = (u16*)(ws + 60424192);
  u16* w9     = S2;  // spans S2..60,948,480
  const size_t WS_NEED = 60948480;
  u16* D   = selout;
  u16* KD  = (u16*)((char*)selout + 393216);
  u16* VD  = (u16*)((char*)selout + 524288);
  int* idx = (int*)((char*)selout + 655360);
  u16* O0 = (u16*)dout;
  u16* O1 = O0 + 4194304;
  u16* O2 = O0 + 8388608;

  if (ws_size < WS_NEED) {
    probe_fill<<<2048, 256, 0, stream>>>(dout, 1000.0f);
    return;
  }

  u16* wcls = O0;
  u16* k1 = S2, *q1 = S2;
  u16* kbuf = O1, *vT = O2;
  u16* qbuf = O0, *ctx = O0;

  sim_argmax<<<200, 64, 0, stream>>>(text, tmem, idx);
  build_d<<<768, 256, 0, stream>>>(memory, idx, D);
  wcls_kernel<<<256, 256, 0, stream>>>(preds, wcls);
  transpose_feats<<<dim3(64, 12, 4), 256, 0, stream>>>(feats, featsT);
  cast_all<<<3584, 256, 0, stream>>>(qw1, qw1c, kw1, kw1c, vw, vwc, ow, owc, qw2, qw2c, kw2, kw2c);

  gemm_std<false><<<dim3(2, 2), 256, 0, stream>>>(kw1c, D, KD, nullptr, nullptr, 256, 768, 768, 768);
  gemm_std<false><<<dim3(2, 2), 256, 0, stream>>>(vwc, D, VD, nullptr, nullptr, 256, 768, 768, 768);

  gemm_std<true><<<dim3(2, 128), 256, 0, stream>>>(wcls, KD, k1, kg1, kb1, 256, 256, 256, 256);
  gemm_std<true><<<dim3(2, 128), 256, 0, stream>>>(k1, kw2c, kbuf, kg2, kb2, 256, 256, 256, 256);
  gemm_swv<<<dim3(128, 2), 256, 0, stream>>>(VD, wcls, vT, vg, vb, 256, 256, 256, 256);
  gemm_std<true><<<dim3(2, 128), 256, 0, stream>>>(featsT, qw1c, q1, qg1, qb1, 256, 768, 768, 768);
  gemm_std<true><<<dim3(2, 128), 256, 0, stream>>>(q1, qw2c, qbuf, qg2, qb2, 256, 256, 256, 256);
  flash_attn<<<dim3(64, 4), 256, 0, stream>>>(qbuf, kbuf, vT, ctx);
  gemm_std<true><<<dim3(6, 128), 256, 0, stream>>>(ctx, owc, selout, og, ob, 768, 256, 256, 256);
  // conv pass 1 (A variant: 128-row blocks): feats half -> raw f32 partial
  repack2<<<288, 256, 0, stream>>>(bw, w9, 0);
  conv_frag<1><<<dim3(128, 6), 256, 0, stream>>>(w9, featsT, dout, nullptr, nullptr);
  // conv pass 2 (B variant: 64-row blocks, 1536 blocks): selout half, +BN+relu
  repack2<<<288, 256, 0, stream>>>(bw, w9, 768);
  conv_ms<<<1536, 256, 0, stream>>>(w9, selout, dout, bg, bb);
}

// Round 18
// 820.350 us; speedup vs baseline: 1.4336x; 1.4336x over previous
//
#include <hip/hip_runtime.h>
#include <stdint.h>

typedef unsigned short u16;
typedef __attribute__((ext_vector_type(8))) short short8;
typedef __attribute__((ext_vector_type(4))) float f32x4;

#define RSQC 0.9999950000374997f  // 1/sqrt(1+1e-5)
#define OUT_ELEMS 12582912        // 4*768*64*64 (f32 elements)

__device__ __forceinline__ float bf2f(u16 u) {
  union { uint32_t i; float f; } v; v.i = ((uint32_t)u) << 16; return v.f;
}
__device__ __forceinline__ u16 f2bf(float f) {
  union { uint32_t i; float f; } v; v.f = f;
  uint32_t i = v.i;
  i += 0x7fffu + ((i >> 16) & 1u);   // RTNE (finite inputs)
  return (u16)(i >> 16);
}
// async global->LDS, 16B/lane; LDS dest = wave-uniform base + lane*16 (HW rule)
__device__ __forceinline__ void gload16(const u16* g, u16* l) {
  __builtin_amdgcn_global_load_lds(
      (const __attribute__((address_space(1))) uint32_t*)g,
      (__attribute__((address_space(3))) uint32_t*)l, 16, 0, 0);
}

// ---------------- diagnostics ----------------
__global__ __launch_bounds__(256) void probe_fill(float* out, float val) {
  for (size_t i = (size_t)blockIdx.x * 256 + threadIdx.x; i < OUT_ELEMS; i += (size_t)gridDim.x * 256)
    out[i] = val;
}

// ---------------- small kernels (f32 inputs) ----------------

__global__ __launch_bounds__(64) void sim_argmax(const float* __restrict__ text,
                                                 const float* __restrict__ tmem,
                                                 int* __restrict__ idx) {
  const int i = blockIdx.x, lane = threadIdx.x;
  const float* t = text + (size_t)i * 768;
  float tr[12];
  float nt = 0.f;
#pragma unroll
  for (int k = 0; k < 12; ++k) { tr[k] = t[lane + k * 64]; nt += tr[k] * tr[k]; }
#pragma unroll
  for (int m = 32; m; m >>= 1) nt += __shfl_xor(nt, m);
  nt = sqrtf(nt);
  float best = -1e30f; int bj = 0;
  for (int j = 0; j < 171; ++j) {
    const float* tc = tmem + (size_t)j * 768;
    float dot = 0.f, nc = 0.f;
#pragma unroll
    for (int k = 0; k < 12; ++k) {
      float y = tc[lane + k * 64];
      dot += tr[k] * y;
      nc += y * y;
    }
#pragma unroll
    for (int m = 32; m; m >>= 1) {
      dot += __shfl_xor(dot, m);
      nc += __shfl_xor(nc, m);
    }
    float s = dot / fmaxf(nt * sqrtf(nc), 1e-8f);
    if (s > best) { best = s; bj = j; }  // strict > keeps first max (ref semantics)
  }
  if (lane == 0) idx[i] = bj;
}

// D[j][c] (256 x 768) bf16 = memory[idx[j]][c], rows >=200 zero
__global__ __launch_bounds__(256) void build_d(const float* __restrict__ memory,
                                               const int* __restrict__ idx,
                                               u16* __restrict__ D) {
  int i = blockIdx.x * 256 + threadIdx.x;  // 256*768
  if (i >= 256 * 768) return;
  int c = i % 768, j = i / 768;
  u16 v = 0;
  if (j < 200) {
    int ii = idx[j];
    ii = ii < 0 ? 0 : (ii > 170 ? 170 : ii);
    v = f2bf(memory[(size_t)ii * 768 + c]);
  }
  D[i] = v;
}

// per-position softmax over 200 classes; 256 blocks x 64 pos, 4 class-quarters/pos.
__global__ __launch_bounds__(256) void wcls_kernel(const float* __restrict__ preds,
                                                   u16* __restrict__ wcls) {
  __shared__ float red[4][64];
  const int tid = threadIdx.x;
  const int p = tid & 63, q = tid >> 6;
  const int pos = blockIdx.x * 64 + p;
  const int b = pos >> 12, hw = pos & 4095;
  const float* pp = preds + (size_t)b * 200 * 4096 + hw;
  const int nlo = q * 50, nhi = nlo + 50;
  float mx = -1e30f;
  for (int n = nlo; n < nhi; ++n) mx = fmaxf(mx, pp[(size_t)n * 4096]);
  red[q][p] = mx;
  __syncthreads();
  const float m = fmaxf(fmaxf(red[0][p], red[1][p]), fmaxf(red[2][p], red[3][p]));
  __syncthreads();
  float s = 0.f;
  for (int n = nlo; n < nhi; ++n) s += __expf(pp[(size_t)n * 4096] - m);
  red[q][p] = s;
  __syncthreads();
  const float inv = 1.f / (red[0][p] + red[1][p] + red[2][p] + red[3][p]);
  u16* w = wcls + (size_t)pos * 256;
#pragma unroll
  for (int c8 = 0; c8 < 8; ++c8) {
    short8 v;
    const int base = q * 64 + c8 * 8;
#pragma unroll
    for (int j = 0; j < 8; ++j) {
      const int n = base + j;
      float e = (n < 200) ? __expf(pp[(size_t)n * 4096] - m) * inv : 0.f;
      v[j] = (short)f2bf(e);
    }
    *(short8*)&w[base] = v;
  }
}

// feats f32 (B,768,4096) -> featsT bf16 (B*4096, 768)
__global__ __launch_bounds__(256) void transpose_feats(const float* __restrict__ feats,
                                                       u16* __restrict__ ft) {
  __shared__ u16 t[64][65];
  const int bz = blockIdx.z, c0 = blockIdx.y * 64, p0 = blockIdx.x * 64;
  const int col = threadIdx.x & 63, row4 = threadIdx.x >> 6;
  const float* src = feats + ((size_t)bz * 768 + c0) * 4096 + p0;
#pragma unroll
  for (int i = 0; i < 16; ++i) {
    int ci = i * 4 + row4;
    t[ci][col] = f2bf(src[(size_t)ci * 4096 + col]);
  }
  __syncthreads();
  u16* dst = ft + ((size_t)bz * 4096 + p0) * 768 + c0;
#pragma unroll
  for (int i = 0; i < 16; ++i) {
    int pi = i * 4 + row4;
    dst[(size_t)pi * 768 + col] = t[col][pi];
  }
}

// fused f32->bf16 cast of the six attention weight matrices
__global__ __launch_bounds__(256) void cast_all(
    const float* __restrict__ s0, u16* __restrict__ d0,
    const float* __restrict__ s1, u16* __restrict__ d1,
    const float* __restrict__ s2, u16* __restrict__ d2,
    const float* __restrict__ s3, u16* __restrict__ d3,
    const float* __restrict__ s4, u16* __restrict__ d4,
    const float* __restrict__ s5, u16* __restrict__ d5) {
  int i = blockIdx.x * 256 + threadIdx.x;  // < 917504
  if (i < 196608) d0[i] = f2bf(s0[i]);
  else if (i < 393216) d1[i - 196608] = f2bf(s1[i - 196608]);
  else if (i < 589824) d2[i - 393216] = f2bf(s2[i - 393216]);
  else if (i < 786432) d3[i - 589824] = f2bf(s3[i - 589824]);
  else if (i < 851968) d4[i - 786432] = f2bf(s4[i - 786432]);
  else if (i < 917504) d5[i - 851968] = f2bf(s5[i - 851968]);
}

// Coalesced fragment repack: lane owns (o, c-oct), reads 288 contiguous bytes
// (8 c x 9 taps f32), writes 9 tap-fragments as wave-contiguous 1KB stores.
__global__ __launch_bounds__(256) void repack2(const float* __restrict__ bw,
                                               u16* __restrict__ w9f, int c_base) {
  const int gid = blockIdx.x * 4 + (threadIdx.x >> 6);  // 0..1151
  const int lane = threadIdx.x & 63;
  const int mfrag = gid % 48, kc = gid / 48;
  const int o = mfrag * 16 + (lane & 15);
  const int c = c_base + kc * 32 + (lane >> 4) * 8;
  const float* src = bw + ((size_t)o * 1536 + c) * 9;
  float v[72];
#pragma unroll
  for (int t = 0; t < 72; ++t) v[t] = src[t];
#pragma unroll
  for (int tap = 0; tap < 9; ++tap) {
    short8 w;
#pragma unroll
    for (int j = 0; j < 8; ++j) w[j] = (short)f2bf(v[j * 9 + tap]);
    *(short8*)&w9f[(((size_t)(kc * 9 + tap) * 48 + mfrag) << 9) + lane * 8] = w;
  }
}

// ---------------- 128x128 MFMA GEMM, double-buffered + bank-swizzled LDS ----
template <bool EP>
__global__ __launch_bounds__(256) void gemm_std(
    const u16* __restrict__ A, const u16* __restrict__ Bt, u16* __restrict__ out,
    const float* __restrict__ g, const float* __restrict__ bia,
    int N, int K, int lda, int ldb) {
  __shared__ __attribute__((aligned(16))) u16 As[2][128 * 32];
  __shared__ __attribute__((aligned(16))) u16 Bs[2][128 * 32];
  const int tid = threadIdx.x, lane = tid & 63, wv = tid >> 6;
  const int wr = wv >> 1, wc = wv & 1;
  const int m0 = blockIdx.y * 128, n0 = blockIdx.x * 128;
  const int r0 = lane >> 2, ksl = (lane & 3) * 8;
  const int wofs = (lane >> 2) * 32 + (((lane & 3) ^ ((lane >> 3) & 3)) << 3);
  const int rsl = (((lane >> 4) ^ ((lane >> 1) & 3)) << 3);
  f32x4 acc[4][4] = {};
  const int nt = K >> 5;

  short8 a0[2], b0[2], a1[2], b1[2];
  auto LOAD = [&](int t, short8 av[2], short8 bv[2]) {
    const int k0 = t << 5;
#pragma unroll
    for (int i = 0; i < 2; ++i) {
      const int row = (wv * 2 + i) * 16 + r0;
      av[i] = *(const short8*)(A + (size_t)(m0 + row) * lda + k0 + ksl);
      bv[i] = *(const short8*)(Bt + (size_t)(n0 + row) * ldb + k0 + ksl);
    }
  };
  auto STORE = [&](int buf, short8 av[2], short8 bv[2]) {
#pragma unroll
    for (int i = 0; i < 2; ++i) {
      const int o = (wv * 2 + i) * 512 + wofs;
      *(short8*)&As[buf][o] = av[i];
      *(short8*)&Bs[buf][o] = bv[i];
    }
  };
  auto COMPUTE = [&](int buf) {
    short8 a[4], b[4];
#pragma unroll
    for (int mi = 0; mi < 4; ++mi)
      a[mi] = *(const short8*)&As[buf][(wr * 4 + mi) * 512 + (lane & 15) * 32 + rsl];
#pragma unroll
    for (int ni = 0; ni < 4; ++ni)
      b[ni] = *(const short8*)&Bs[buf][(wc * 4 + ni) * 512 + (lane & 15) * 32 + rsl];
#pragma unroll
    for (int mi = 0; mi < 4; ++mi)
#pragma unroll
      for (int ni = 0; ni < 4; ++ni)
        acc[mi][ni] = __builtin_amdgcn_mfma_f32_16x16x32_bf16(a[mi], b[ni], acc[mi][ni], 0, 0, 0);
  };

  LOAD(0, a0, b0);
  for (int t = 0; t < nt; t += 2) {
    STORE(0, a0, b0);
    __syncthreads();
    LOAD(t + 1, a1, b1);
    COMPUTE(0);
    STORE(1, a1, b1);
    __syncthreads();
    if (t + 2 < nt) LOAD(t + 2, a0, b0);
    COMPUTE(1);
  }
  const int mb = m0 + wr * 64 + ((lane >> 4) << 2);
  const int nb = n0 + wc * 64 + (lane & 15);
#pragma unroll
  for (int ni = 0; ni < 4; ++ni) {
    const int n = nb + ni * 16;
    float s = 1.f, bb_ = 0.f;
    if (EP) { s = g[n] * RSQC; bb_ = bia[n]; }
#pragma unroll
    for (int mi = 0; mi < 4; ++mi)
#pragma unroll
      for (int r = 0; r < 4; ++r) {
        float v = acc[mi][ni][r];
        if (EP) v = fmaxf(v * s + bb_, 0.f);
        out[(size_t)(mb + mi * 16 + r) * N + n] = f2bf(v);
      }
  }
}

// Swapped GEMM (vT path): out bf16 (b, m, pos); BN per-m.
__global__ __launch_bounds__(256) void gemm_swv(
    const u16* __restrict__ A, const u16* __restrict__ Bt, u16* __restrict__ out,
    const float* __restrict__ g, const float* __restrict__ bia,
    int Mtot, int K, int lda, int ldb) {
  __shared__ __attribute__((aligned(16))) u16 As[2][128 * 32];
  __shared__ __attribute__((aligned(16))) u16 Bs[2][128 * 32];
  const int tid = threadIdx.x, lane = tid & 63, wv = tid >> 6;
  const int wr = wv >> 1, wc = wv & 1;
  const int m0 = blockIdx.y * 128, n0 = blockIdx.x * 128;
  const int r0 = lane >> 2, ksl = (lane & 3) * 8;
  const int wofs = (lane >> 2) * 32 + (((lane & 3) ^ ((lane >> 3) & 3)) << 3);
  const int rsl = (((lane >> 4) ^ ((lane >> 1) & 3)) << 3);
  f32x4 acc[4][4] = {};
  const int nt = K >> 5;

  short8 a0[2], b0[2], a1[2], b1[2];
  auto LOAD = [&](int t, short8 av[2], short8 bv[2]) {
    const int k0 = t << 5;
#pragma unroll
    for (int i = 0; i < 2; ++i) {
      const int row = (wv * 2 + i) * 16 + r0;
      av[i] = *(const short8*)(A + (size_t)(m0 + row) * lda + k0 + ksl);
      bv[i] = *(const short8*)(Bt + (size_t)(n0 + row) * ldb + k0 + ksl);
    }
  };
  auto STORE = [&](int buf, short8 av[2], short8 bv[2]) {
#pragma unroll
    for (int i = 0; i < 2; ++i) {
      const int o = (wv * 2 + i) * 512 + wofs;
      *(short8*)&As[buf][o] = av[i];
      *(short8*)&Bs[buf][o] = bv[i];
    }
  };
  auto COMPUTE = [&](int buf) {
    short8 a[4], b[4];
#pragma unroll
    for (int mi = 0; mi < 4; ++mi)
      a[mi] = *(const short8*)&As[buf][(wr * 4 + mi) * 512 + (lane & 15) * 32 + rsl];
#pragma unroll
    for (int ni = 0; ni < 4; ++ni)
      b[ni] = *(const short8*)&Bs[buf][(wc * 4 + ni) * 512 + (lane & 15) * 32 + rsl];
#pragma unroll
    for (int mi = 0; mi < 4; ++mi)
#pragma unroll
      for (int ni = 0; ni < 4; ++ni)
        acc[mi][ni] = __builtin_amdgcn_mfma_f32_16x16x32_bf16(a[mi], b[ni], acc[mi][ni], 0, 0, 0);
  };

  LOAD(0, a0, b0);
  for (int t = 0; t < nt; t += 2) {
    STORE(0, a0, b0);
    __syncthreads();
    LOAD(t + 1, a1, b1);
    COMPUTE(0);
    STORE(1, a1, b1);
    __syncthreads();
    if (t + 2 < nt) LOAD(t + 2, a0, b0);
    COMPUTE(1);
  }
  const int mb = m0 + wr * 64 + ((lane >> 4) << 2);
  const int nb = n0 + wc * 64 + (lane & 15);
#pragma unroll
  for (int mi = 0; mi < 4; ++mi)
#pragma unroll
    for (int r = 0; r < 4; ++r) {
      const int m = mb + mi * 16 + r;
      const float s = g[m] * RSQC, bb_ = bia[m];
#pragma unroll
      for (int ni = 0; ni < 4; ++ni) {
        const int n = nb + ni * 16;
        out[((size_t)(n >> 12) * Mtot + m) * 4096 + (n & 4095)] =
            f2bf(fmaxf(acc[mi][ni][r] * s + bb_, 0.f));
      }
    }
}

// ---------------- implicit 3x3 conv, 128-row blocks (R15-proven) ----------------
// MODE 1: store raw f32; MODE 2: in-place +BN+relu.
template <int MODE>
__global__ __launch_bounds__(256) void conv_frag(
    const u16* __restrict__ Af, const u16* __restrict__ X, float* out,
    const float* __restrict__ g, const float* __restrict__ bia) {
  __shared__ __attribute__((aligned(16))) u16 Hb[2][264 * 32];
  const int tid = threadIdx.x, lane = tid & 63, wv = tid >> 6;
  const int wr = wv >> 1, wc = wv & 1;
  const int id = blockIdx.y * 128 + blockIdx.x;
  const int xcd = id & 7, sl = id >> 3;
  const int m0 = (sl % 6) * 128;
  const int n0 = (xcd * 16 + sl / 6) * 128;
  f32x4 acc[4][4] = {};

  int vmask[4];
#pragma unroll
  for (int i = 0; i < 4; ++i) {
    const int hw = (n0 + wc * 64 + i * 16 + (lane & 15)) & 4095;
    const int h = hw >> 6, w = hw & 63;
    int m = 0;
#pragma unroll
    for (int t = 0; t < 9; ++t)
      if ((unsigned)(h + t / 3 - 1) < 64u && (unsigned)(w + t % 3 - 1) < 64u) m |= 1 << t;
    vmask[i] = m;
  }

  const int fb = (m0 >> 4) + wr * 4;
  auto aload = [&](int kc, int tap, short8 d[4]) {
    const u16* base = Af + ((size_t)((kc * 9 + tap) * 48 + fb) << 9) + lane * 8;
#pragma unroll
    for (int mi = 0; mi < 4; ++mi) d[mi] = *(const short8*)(base + (mi << 9));
  };
  auto hstage = [&](int kc, int buf) {
#pragma unroll
    for (int j = 0; j < 5; ++j) {
      const int cid = tid + j * 256;
      if (cid < 1032) {
        int q = n0 - 65 + (cid >> 2);
        q = q < 0 ? 0 : (q > 16383 ? 16383 : q);  // clamped rows only used masked
        const int row = cid >> 2;
        const int s = (cid & 3) ^ ((row >> 1) & 3);
        gload16(X + (size_t)q * 768 + kc * 32 + s * 8, &Hb[buf][(size_t)cid * 8]);
      }
    }
  };

  hstage(0, 0);
  short8 acur[4], anxt[4];
  aload(0, 0, acur);
  __syncthreads();
  int p = 0;
  for (int kc = 0; kc < 24; ++kc) {
    if (kc < 23) hstage(kc + 1, p ^ 1);
#pragma unroll
    for (int tap = 0; tap < 9; ++tap) {
      const int nk = (tap == 8) ? (kc == 23 ? 23 : kc + 1) : kc;
      const int ntp = (tap == 8) ? 0 : tap + 1;
      aload(nk, ntp, anxt);
      const int shift = (tap / 3 - 1) * 64 + (tap % 3 - 1);
#pragma unroll
      for (int ni = 0; ni < 4; ++ni) {
        const int hrow = wc * 64 + ni * 16 + (lane & 15) + 65 + shift;
        short8 bv = *(const short8*)((const char*)&Hb[p][0] + hrow * 64 +
                                     (((lane >> 4) ^ ((hrow >> 1) & 3)) << 4));
        short8 z = {};
        if (!((vmask[ni] >> tap) & 1)) bv = z;
#pragma unroll
        for (int mi = 0; mi < 4; ++mi)
          acc[mi][ni] = __builtin_amdgcn_mfma_f32_16x16x32_bf16(acur[mi], bv, acc[mi][ni], 0, 0, 0);
      }
#pragma unroll
      for (int mi = 0; mi < 4; ++mi) acur[mi] = anxt[mi];
    }
    if (kc < 23) {
      __syncthreads();
      p ^= 1;
    }
  }
  const int mb = m0 + wr * 64 + ((lane >> 4) << 2);
  const int nb = n0 + wc * 64 + (lane & 15);
#pragma unroll
  for (int mi = 0; mi < 4; ++mi)
#pragma unroll
    for (int r = 0; r < 4; ++r) {
      const int m = mb + mi * 16 + r;
      float s = 0.f, bb_ = 0.f;
      if (MODE == 2) { s = g[m] * RSQC; bb_ = bia[m]; }
#pragma unroll
      for (int ni = 0; ni < 4; ++ni) {
        const int n = nb + ni * 16;
        const size_t oidx = ((size_t)(n >> 12) * 768 + m) * 4096 + (n & 4095);
        if (MODE == 1) out[oidx] = acc[mi][ni][r];
        else out[oidx] = fmaxf((acc[mi][ni][r] + out[oidx]) * s + bb_, 0.f);
      }
    }
}

// ---------------- 64-row m-tile variant, 1536 blocks (conv pass 2) ----------------
__global__ __launch_bounds__(256) void conv_ms(
    const u16* __restrict__ Af, const u16* __restrict__ X, float* out,
    const float* __restrict__ g, const float* __restrict__ bia) {
  __shared__ __attribute__((aligned(16))) u16 Hb[2][264 * 32];
  const int tid = threadIdx.x, lane = tid & 63, wv = tid >> 6;
  const int wr = wv >> 1, wc = wv & 1;
  const int id = blockIdx.x;
  const int xcd = id & 7, sl = id >> 3;  // sl 0..191
  const int m0 = (sl % 12) * 64;
  const int n0 = (xcd * 16 + sl / 12) * 128;
  f32x4 acc[2][4] = {};

  int vmask[4];
#pragma unroll
  for (int i = 0; i < 4; ++i) {
    const int hw = (n0 + wc * 64 + i * 16 + (lane & 15)) & 4095;
    const int h = hw >> 6, w = hw & 63;
    int m = 0;
#pragma unroll
    for (int t = 0; t < 9; ++t)
      if ((unsigned)(h + t / 3 - 1) < 64u && (unsigned)(w + t % 3 - 1) < 64u) m |= 1 << t;
    vmask[i] = m;
  }

  const int fb = (m0 >> 4) + wr * 2;
  auto aload = [&](int kc, int tap, short8 d[2]) {
    const u16* base = Af + ((size_t)((kc * 9 + tap) * 48 + fb) << 9) + lane * 8;
#pragma unroll
    for (int mi = 0; mi < 2; ++mi) d[mi] = *(const short8*)(base + (mi << 9));
  };
  auto hstage = [&](int kc, int buf) {
#pragma unroll
    for (int j = 0; j < 5; ++j) {
      const int cid = tid + j * 256;
      if (cid < 1032) {
        int q = n0 - 65 + (cid >> 2);
        q = q < 0 ? 0 : (q > 16383 ? 16383 : q);
        const int row = cid >> 2;
        const int s = (cid & 3) ^ ((row >> 1) & 3);
        gload16(X + (size_t)q * 768 + kc * 32 + s * 8, &Hb[buf][(size_t)cid * 8]);
      }
    }
  };

  hstage(0, 0);
  short8 acur[2], anxt[2];
  aload(0, 0, acur);
  __syncthreads();
  int p = 0;
  for (int kc = 0; kc < 24; ++kc) {
    if (kc < 23) hstage(kc + 1, p ^ 1);
#pragma unroll
    for (int tap = 0; tap < 9; ++tap) {
      const int nk = (tap == 8) ? (kc == 23 ? 23 : kc + 1) : kc;
      const int ntp = (tap == 8) ? 0 : tap + 1;
      aload(nk, ntp, anxt);
      const int shift = (tap / 3 - 1) * 64 + (tap % 3 - 1);
#pragma unroll
      for (int ni = 0; ni < 4; ++ni) {
        const int hrow = wc * 64 + ni * 16 + (lane & 15) + 65 + shift;
        short8 bv = *(const short8*)((const char*)&Hb[p][0] + hrow * 64 +
                                     (((lane >> 4) ^ ((hrow >> 1) & 3)) << 4));
        short8 z = {};
        if (!((vmask[ni] >> tap) & 1)) bv = z;
#pragma unroll
        for (int mi = 0; mi < 2; ++mi)
          acc[mi][ni] = __builtin_amdgcn_mfma_f32_16x16x32_bf16(acur[mi], bv, acc[mi][ni], 0, 0, 0);
      }
#pragma unroll
      for (int mi = 0; mi < 2; ++mi) acur[mi] = anxt[mi];
    }
    if (kc < 23) {
      __syncthreads();
      p ^= 1;
    }
  }
  const int mb = m0 + wr * 32 + ((lane >> 4) << 2);
  const int nb = n0 + wc * 64 + (lane & 15);
#pragma unroll
  for (int mi = 0; mi < 2; ++mi)
#pragma unroll
    for (int r = 0; r < 4; ++r) {
      const int m = mb + mi * 16 + r;
      const float s = g[m] * RSQC, bb_ = bia[m];
#pragma unroll
      for (int ni = 0; ni < 4; ++ni) {
        const int n = nb + ni * 16;
        const size_t oidx = ((size_t)(n >> 12) * 768 + m) * 4096 + (n & 4095);
        out[oidx] = fmaxf((acc[mi][ni][r] + out[oidx]) * s + bb_, 0.f);
      }
    }
}

// ---------------- flash attention (R12-proven: 256 thr, QBLK=64, grid (64,4)) ----
__global__ __launch_bounds__(256) void flash_attn(const u16* Q,
                                                  const u16* __restrict__ Kg,
                                                  const u16* __restrict__ Vt,
                                                  u16* ctx) {
  __shared__ __attribute__((aligned(16))) u16 KVs[64 * 256];
  __shared__ __attribute__((aligned(16))) u16 Ps[4096];
  const int tid = threadIdx.x, lane = tid & 63, wv = tid >> 6;
  const int b = blockIdx.y, q0 = blockIdx.x * 64;
  const u16* qb = Q + ((size_t)b * 4096 + q0) * 256;
  const u16* kb = Kg + (size_t)b * 4096 * 256;
  const u16* vb = Vt + (size_t)b * 256 * 4096;
  const float scale = 0.0625f;

  short8 qf[8];
  {
    const int arow = wv * 16 + (lane & 15);
    const u16* qrow = qb + (size_t)arow * 256 + (lane >> 4) * 8;
#pragma unroll
    for (int kk = 0; kk < 8; ++kk) qf[kk] = *(const short8*)(qrow + kk * 32);
  }
  float mreg[4] = {-1e30f, -1e30f, -1e30f, -1e30f};
  float lsum[4] = {0.f, 0.f, 0.f, 0.f};
  f32x4 o[16] = {};

  for (int t = 0; t < 64; ++t) {
    {
      const int r = tid >> 5, sb = (tid & 31) * 16;
      const char* ksrc = (const char*)(kb + (size_t)t * 64 * 256);
#pragma unroll
      for (int i = 0; i < 8; ++i) {
        int row = i * 8 + r;
        short8 v = *(const short8*)(ksrc + (size_t)row * 512 + sb);
        *(short8*)((char*)KVs + row * 512 + (sb ^ ((row & 7) << 4))) = v;
      }
    }
    __syncthreads();
    f32x4 s4[4] = {};
    __builtin_amdgcn_s_setprio(1);
#pragma unroll
    for (int kk = 0; kk < 8; ++kk) {
      const int cb = (kk * 32 + ((lane >> 4) * 8)) * 2;
#pragma unroll
      for (int ni = 0; ni < 4; ++ni) {
        const int brow = ni * 16 + (lane & 15);
        short8 bb = *(const short8*)((const char*)KVs + brow * 512 + (cb ^ ((brow & 7) << 4)));
        s4[ni] = __builtin_amdgcn_mfma_f32_16x16x32_bf16(qf[kk], bb, s4[ni], 0, 0, 0);
      }
    }
    __builtin_amdgcn_s_setprio(0);
    float al[4], p[4][4];
#pragma unroll
    for (int r = 0; r < 4; ++r) {
      float v0 = fmaxf(fmaxf(s4[0][r], s4[1][r]), fmaxf(s4[2][r], s4[3][r]));
      v0 = fmaxf(v0, __shfl_xor(v0, 1));
      v0 = fmaxf(v0, __shfl_xor(v0, 2));
      v0 = fmaxf(v0, __shfl_xor(v0, 4));
      v0 = fmaxf(v0, __shfl_xor(v0, 8));
      const float mn = fmaxf(mreg[r], v0 * scale);
      al[r] = __expf(mreg[r] - mn);
      mreg[r] = mn;
      float srow = 0.f;
#pragma unroll
      for (int ni = 0; ni < 4; ++ni) {
        float pv = __expf(s4[ni][r] * scale - mn);
        p[ni][r] = pv;
        srow += pv;
      }
      srow += __shfl_xor(srow, 1);
      srow += __shfl_xor(srow, 2);
      srow += __shfl_xor(srow, 4);
      srow += __shfl_xor(srow, 8);
      lsum[r] = lsum[r] * al[r] + srow;
    }
#pragma unroll
    for (int nf = 0; nf < 16; ++nf)
#pragma unroll
      for (int r = 0; r < 4; ++r) o[nf][r] *= al[r];
    {
      char* pbase = (char*)Ps + wv * 2048;
#pragma unroll
      for (int ni = 0; ni < 4; ++ni)
#pragma unroll
        for (int r = 0; r < 4; ++r) {
          const int row = ((lane >> 4) << 2) + r, col = ni * 16 + (lane & 15);
          *(u16*)(pbase + row * 128 + ((col * 2) ^ ((row & 7) << 4))) = f2bf(p[ni][r]);
        }
    }
    __syncthreads();
    {
      const int slot = tid & 7;
#pragma unroll
      for (int i = 0; i < 8; ++i) {
        const int cc = i * 32 + (tid >> 3);
        short8 v = *(const short8*)((const char*)vb + ((size_t)cc * 4096 + t * 64) * 2 + slot * 16);
        *(short8*)((char*)KVs + cc * 128 + ((slot * 16) ^ ((cc & 7) << 4))) = v;
      }
    }
    __syncthreads();
    short8 pa[2];
#pragma unroll
    for (int kk = 0; kk < 2; ++kk) {
      const int row = lane & 15;
      const int cb = (kk * 32 + ((lane >> 4) * 8)) * 2;
      pa[kk] = *(const short8*)((const char*)Ps + wv * 2048 + row * 128 + (cb ^ ((row & 7) << 4)));
    }
    __builtin_amdgcn_s_setprio(1);
#pragma unroll
    for (int nf = 0; nf < 16; ++nf) {
      const int crow = nf * 16 + (lane & 15);
#pragma unroll
      for (int kk = 0; kk < 2; ++kk) {
        const int kb2 = (kk * 32 + ((lane >> 4) * 8)) * 2;
        short8 bb = *(const short8*)((const char*)KVs + crow * 128 + (kb2 ^ ((crow & 7) << 4)));
        o[nf] = __builtin_amdgcn_mfma_f32_16x16x32_bf16(pa[kk], bb, o[nf], 0, 0, 0);
      }
    }
    __builtin_amdgcn_s_setprio(0);
    __syncthreads();
  }
  u16* cb_ = ctx + ((size_t)b * 4096 + q0) * 256;
#pragma unroll
  for (int r = 0; r < 4; ++r) {
    const int row = wv * 16 + ((lane >> 4) << 2) + r;
    const float inv = 1.f / lsum[r];
#pragma unroll
    for (int nf = 0; nf < 16; ++nf) {
      const int col = nf * 16 + (lane & 15);
      cb_[(size_t)row * 256 + col] = f2bf(o[nf][r] * inv);
    }
  }
}

// ---------------- launch ----------------

extern "C" void kernel_launch(void* const* d_in, const int* in_sizes, int n_in,
                              void* d_out, int out_size, void* d_ws, size_t ws_size,
                              hipStream_t stream) {
  (void)in_sizes; (void)n_in; (void)out_size;
  const float* feats  = (const float*)d_in[0];
  const float* preds  = (const float*)d_in[1];
  const float* text   = (const float*)d_in[2];
  const float* memory = (const float*)d_in[3];
  const float* tmem   = (const float*)d_in[4];
  const float* qw1 = (const float*)d_in[5];  const float* qg1 = (const float*)d_in[6];  const float* qb1 = (const float*)d_in[7];
  const float* qw2 = (const float*)d_in[8];  const float* qg2 = (const float*)d_in[9];  const float* qb2 = (const float*)d_in[10];
  const float* kw1 = (const float*)d_in[11]; const float* kg1 = (const float*)d_in[12]; const float* kb1 = (const float*)d_in[13];
  const float* kw2 = (const float*)d_in[14]; const float* kg2 = (const float*)d_in[15]; const float* kb2 = (const float*)d_in[16];
  const float* vw  = (const float*)d_in[17]; const float* vg  = (const float*)d_in[18]; const float* vb  = (const float*)d_in[19];
  const float* ow  = (const float*)d_in[20]; const float* og  = (const float*)d_in[21]; const float* ob  = (const float*)d_in[22];
  const float* bw  = (const float*)d_in[23]; const float* bg  = (const float*)d_in[24]; const float* bb  = (const float*)d_in[25];

  float* dout = (float*)d_out;  // 12,582,912 f32
  char* ws = (char*)d_ws;
  u16* featsT = (u16*)(ws);                           // 25,165,824 B
  u16* selout = (u16*)(ws + 25165824);                // 25,165,824 B
  u16* S2     = (u16*)(ws + 50331648);                //  8,388,608 B (k1 -> q1)
  u16* qw1c   = (u16*)(ws + 58720256);
  u16* kw1c   = (u16*)(ws + 59113472);
  u16* vwc    = (u16*)(ws + 59506688);
  u16* owc    = (u16*)(ws + 59899904);
  u16* qw2c   = (u16*)(ws + 60293120);
  u16* kw2c   = (u16*)(ws + 60424192);
  u16* w9     = S2;  // spans S2..60,948,480
  const size_t WS_NEED = 60948480;
  u16* D   = selout;
  u16* KD  = (u16*)((char*)selout + 393216);
  u16* VD  = (u16*)((char*)selout + 524288);
  int* idx = (int*)((char*)selout + 655360);
  u16* O0 = (u16*)dout;
  u16* O1 = O0 + 4194304;
  u16* O2 = O0 + 8388608;

  if (ws_size < WS_NEED) {
    probe_fill<<<2048, 256, 0, stream>>>(dout, 1000.0f);
    return;
  }

  u16* wcls = O0;
  u16* k1 = S2, *q1 = S2;
  u16* kbuf = O1, *vT = O2;
  u16* qbuf = O0, *ctx = O0;

  sim_argmax<<<200, 64, 0, stream>>>(text, tmem, idx);
  build_d<<<768, 256, 0, stream>>>(memory, idx, D);
  wcls_kernel<<<256, 256, 0, stream>>>(preds, wcls);
  transpose_feats<<<dim3(64, 12, 4), 256, 0, stream>>>(feats, featsT);
  cast_all<<<3584, 256, 0, stream>>>(qw1, qw1c, kw1, kw1c, vw, vwc, ow, owc, qw2, qw2c, kw2, kw2c);

  gemm_std<false><<<dim3(2, 2), 256, 0, stream>>>(kw1c, D, KD, nullptr, nullptr, 256, 768, 768, 768);
  gemm_std<false><<<dim3(2, 2), 256, 0, stream>>>(vwc, D, VD, nullptr, nullptr, 256, 768, 768, 768);

  gemm_std<true><<<dim3(2, 128), 256, 0, stream>>>(wcls, KD, k1, kg1, kb1, 256, 256, 256, 256);
  gemm_std<true><<<dim3(2, 128), 256, 0, stream>>>(k1, kw2c, kbuf, kg2, kb2, 256, 256, 256, 256);
  gemm_swv<<<dim3(128, 2), 256, 0, stream>>>(VD, wcls, vT, vg, vb, 256, 256, 256, 256);
  gemm_std<true><<<dim3(2, 128), 256, 0, stream>>>(featsT, qw1c, q1, qg1, qb1, 256, 768, 768, 768);
  gemm_std<true><<<dim3(2, 128), 256, 0, stream>>>(q1, qw2c, qbuf, qg2, qb2, 256, 256, 256, 256);
  flash_attn<<<dim3(64, 4), 256, 0, stream>>>(qbuf, kbuf, vT, ctx);
  gemm_std<true><<<dim3(6, 128), 256, 0, stream>>>(ctx, owc, selout, og, ob, 768, 256, 256, 256);
  // conv pass 1 (128-row blocks): feats half -> raw f32 partial
  repack2<<<288, 256, 0, stream>>>(bw, w9, 0);
  conv_frag<1><<<dim3(128, 6), 256, 0, stream>>>(w9, featsT, dout, nullptr, nullptr);
  // conv pass 2 (64-row blocks, 1536 blocks): selout half, +BN+relu
  repack2<<<288, 256, 0, stream>>>(bw, w9, 768);
  conv_ms<<<1536, 256, 0, stream>>>(w9, selout, dout, bg, bb);
}

// Round 19
// 792.850 us; speedup vs baseline: 1.4833x; 1.0347x over previous
//
#include <hip/hip_runtime.h>
#include <stdint.h>

typedef unsigned short u16;
typedef __attribute__((ext_vector_type(8))) short short8;
typedef __attribute__((ext_vector_type(4))) float f32x4;

#define RSQC 0.9999950000374997f  // 1/sqrt(1+1e-5)
#define OUT_ELEMS 12582912        // 4*768*64*64 (f32 elements)

__device__ __forceinline__ float bf2f(u16 u) {
  union { uint32_t i; float f; } v; v.i = ((uint32_t)u) << 16; return v.f;
}
__device__ __forceinline__ u16 f2bf(float f) {
  union { uint32_t i; float f; } v; v.f = f;
  uint32_t i = v.i;
  i += 0x7fffu + ((i >> 16) & 1u);   // RTNE (finite inputs)
  return (u16)(i >> 16);
}
// async global->LDS, 16B/lane; LDS dest = wave-uniform base + lane*16 (HW rule)
__device__ __forceinline__ void gload16(const u16* g, u16* l) {
  __builtin_amdgcn_global_load_lds(
      (const __attribute__((address_space(1))) uint32_t*)g,
      (__attribute__((address_space(3))) uint32_t*)l, 16, 0, 0);
}

// ---------------- diagnostics ----------------
__global__ __launch_bounds__(256) void probe_fill(float* out, float val) {
  for (size_t i = (size_t)blockIdx.x * 256 + threadIdx.x; i < OUT_ELEMS; i += (size_t)gridDim.x * 256)
    out[i] = val;
}

// ---------------- small kernels (f32 inputs) ----------------

__global__ __launch_bounds__(64) void sim_argmax(const float* __restrict__ text,
                                                 const float* __restrict__ tmem,
                                                 int* __restrict__ idx) {
  const int i = blockIdx.x, lane = threadIdx.x;
  const float* t = text + (size_t)i * 768;
  float tr[12];
  float nt = 0.f;
#pragma unroll
  for (int k = 0; k < 12; ++k) { tr[k] = t[lane + k * 64]; nt += tr[k] * tr[k]; }
#pragma unroll
  for (int m = 32; m; m >>= 1) nt += __shfl_xor(nt, m);
  nt = sqrtf(nt);
  float best = -1e30f; int bj = 0;
  for (int j = 0; j < 171; ++j) {
    const float* tc = tmem + (size_t)j * 768;
    float dot = 0.f, nc = 0.f;
#pragma unroll
    for (int k = 0; k < 12; ++k) {
      float y = tc[lane + k * 64];
      dot += tr[k] * y;
      nc += y * y;
    }
#pragma unroll
    for (int m = 32; m; m >>= 1) {
      dot += __shfl_xor(dot, m);
      nc += __shfl_xor(nc, m);
    }
    float s = dot / fmaxf(nt * sqrtf(nc), 1e-8f);
    if (s > best) { best = s; bj = j; }  // strict > keeps first max (ref semantics)
  }
  if (lane == 0) idx[i] = bj;
}

// D[j][c] (256 x 768) bf16 = memory[idx[j]][c], rows >=200 zero
__global__ __launch_bounds__(256) void build_d(const float* __restrict__ memory,
                                               const int* __restrict__ idx,
                                               u16* __restrict__ D) {
  int i = blockIdx.x * 256 + threadIdx.x;  // 256*768
  if (i >= 256 * 768) return;
  int c = i % 768, j = i / 768;
  u16 v = 0;
  if (j < 200) {
    int ii = idx[j];
    ii = ii < 0 ? 0 : (ii > 170 ? 170 : ii);
    v = f2bf(memory[(size_t)ii * 768 + c]);
  }
  D[i] = v;
}

// per-position softmax over 200 classes; 256 blocks x 64 pos, 4 class-quarters/pos.
__global__ __launch_bounds__(256) void wcls_kernel(const float* __restrict__ preds,
                                                   u16* __restrict__ wcls) {
  __shared__ float red[4][64];
  const int tid = threadIdx.x;
  const int p = tid & 63, q = tid >> 6;
  const int pos = blockIdx.x * 64 + p;
  const int b = pos >> 12, hw = pos & 4095;
  const float* pp = preds + (size_t)b * 200 * 4096 + hw;
  const int nlo = q * 50, nhi = nlo + 50;
  float mx = -1e30f;
  for (int n = nlo; n < nhi; ++n) mx = fmaxf(mx, pp[(size_t)n * 4096]);
  red[q][p] = mx;
  __syncthreads();
  const float m = fmaxf(fmaxf(red[0][p], red[1][p]), fmaxf(red[2][p], red[3][p]));
  __syncthreads();
  float s = 0.f;
  for (int n = nlo; n < nhi; ++n) s += __expf(pp[(size_t)n * 4096] - m);
  red[q][p] = s;
  __syncthreads();
  const float inv = 1.f / (red[0][p] + red[1][p] + red[2][p] + red[3][p]);
  u16* w = wcls + (size_t)pos * 256;
#pragma unroll
  for (int c8 = 0; c8 < 8; ++c8) {
    short8 v;
    const int base = q * 64 + c8 * 8;
#pragma unroll
    for (int j = 0; j < 8; ++j) {
      const int n = base + j;
      float e = (n < 200) ? __expf(pp[(size_t)n * 4096] - m) * inv : 0.f;
      v[j] = (short)f2bf(e);
    }
    *(short8*)&w[base] = v;
  }
}

// feats f32 (B,768,4096) -> featsT bf16 (B*4096, 768)
__global__ __launch_bounds__(256) void transpose_feats(const float* __restrict__ feats,
                                                       u16* __restrict__ ft) {
  __shared__ u16 t[64][65];
  const int bz = blockIdx.z, c0 = blockIdx.y * 64, p0 = blockIdx.x * 64;
  const int col = threadIdx.x & 63, row4 = threadIdx.x >> 6;
  const float* src = feats + ((size_t)bz * 768 + c0) * 4096 + p0;
#pragma unroll
  for (int i = 0; i < 16; ++i) {
    int ci = i * 4 + row4;
    t[ci][col] = f2bf(src[(size_t)ci * 4096 + col]);
  }
  __syncthreads();
  u16* dst = ft + ((size_t)bz * 4096 + p0) * 768 + c0;
#pragma unroll
  for (int i = 0; i < 16; ++i) {
    int pi = i * 4 + row4;
    dst[(size_t)pi * 768 + col] = t[col][pi];
  }
}

// fused f32->bf16 cast of the six attention weight matrices
__global__ __launch_bounds__(256) void cast_all(
    const float* __restrict__ s0, u16* __restrict__ d0,
    const float* __restrict__ s1, u16* __restrict__ d1,
    const float* __restrict__ s2, u16* __restrict__ d2,
    const float* __restrict__ s3, u16* __restrict__ d3,
    const float* __restrict__ s4, u16* __restrict__ d4,
    const float* __restrict__ s5, u16* __restrict__ d5) {
  int i = blockIdx.x * 256 + threadIdx.x;  // < 917504
  if (i < 196608) d0[i] = f2bf(s0[i]);
  else if (i < 393216) d1[i - 196608] = f2bf(s1[i - 196608]);
  else if (i < 589824) d2[i - 393216] = f2bf(s2[i - 393216]);
  else if (i < 786432) d3[i - 589824] = f2bf(s3[i - 589824]);
  else if (i < 851968) d4[i - 786432] = f2bf(s4[i - 786432]);
  else if (i < 917504) d5[i - 851968] = f2bf(s5[i - 851968]);
}

// Coalesced fragment repack: lane owns (o, c-oct), reads 288 contiguous bytes
// (8 c x 9 taps f32), writes 9 tap-fragments as wave-contiguous 1KB stores.
__global__ __launch_bounds__(256) void repack2(const float* __restrict__ bw,
                                               u16* __restrict__ w9f, int c_base) {
  const int gid = blockIdx.x * 4 + (threadIdx.x >> 6);  // 0..1151
  const int lane = threadIdx.x & 63;
  const int mfrag = gid % 48, kc = gid / 48;
  const int o = mfrag * 16 + (lane & 15);
  const int c = c_base + kc * 32 + (lane >> 4) * 8;
  const float* src = bw + ((size_t)o * 1536 + c) * 9;
  float v[72];
#pragma unroll
  for (int t = 0; t < 72; ++t) v[t] = src[t];
#pragma unroll
  for (int tap = 0; tap < 9; ++tap) {
    short8 w;
#pragma unroll
    for (int j = 0; j < 8; ++j) w[j] = (short)f2bf(v[j * 9 + tap]);
    *(short8*)&w9f[(((size_t)(kc * 9 + tap) * 48 + mfrag) << 9) + lane * 8] = w;
  }
}

// ---------------- 128x128 MFMA GEMM body (R15-proven math, tile origin passed) ----
// As/Bs: 2 x 4096 u16 LDS buffers.
template <bool EP>
__device__ __forceinline__ void gemm_std_body(
    u16* As, u16* Bs,
    const u16* __restrict__ A, const u16* __restrict__ Bt, u16* __restrict__ out,
    const float* __restrict__ g, const float* __restrict__ bia,
    int N, int K, int lda, int ldb, int m0, int n0) {
  const int tid = threadIdx.x, lane = tid & 63, wv = tid >> 6;
  const int wr = wv >> 1, wc = wv & 1;
  const int r0 = lane >> 2, ksl = (lane & 3) * 8;
  const int wofs = (lane >> 2) * 32 + (((lane & 3) ^ ((lane >> 3) & 3)) << 3);
  const int rsl = (((lane >> 4) ^ ((lane >> 1) & 3)) << 3);
  f32x4 acc[4][4] = {};
  const int nt = K >> 5;

  short8 a0[2], b0[2], a1[2], b1[2];
  auto LOAD = [&](int t, short8 av[2], short8 bv[2]) {
    const int k0 = t << 5;
#pragma unroll
    for (int i = 0; i < 2; ++i) {
      const int row = (wv * 2 + i) * 16 + r0;
      av[i] = *(const short8*)(A + (size_t)(m0 + row) * lda + k0 + ksl);
      bv[i] = *(const short8*)(Bt + (size_t)(n0 + row) * ldb + k0 + ksl);
    }
  };
  auto STORE = [&](int buf, short8 av[2], short8 bv[2]) {
#pragma unroll
    for (int i = 0; i < 2; ++i) {
      const int o = buf * 4096 + (wv * 2 + i) * 512 + wofs;
      *(short8*)&As[o] = av[i];
      *(short8*)&Bs[o] = bv[i];
    }
  };
  auto COMPUTE = [&](int buf) {
    short8 a[4], b[4];
#pragma unroll
    for (int mi = 0; mi < 4; ++mi)
      a[mi] = *(const short8*)&As[buf * 4096 + (wr * 4 + mi) * 512 + (lane & 15) * 32 + rsl];
#pragma unroll
    for (int ni = 0; ni < 4; ++ni)
      b[ni] = *(const short8*)&Bs[buf * 4096 + (wc * 4 + ni) * 512 + (lane & 15) * 32 + rsl];
#pragma unroll
    for (int mi = 0; mi < 4; ++mi)
#pragma unroll
      for (int ni = 0; ni < 4; ++ni)
        acc[mi][ni] = __builtin_amdgcn_mfma_f32_16x16x32_bf16(a[mi], b[ni], acc[mi][ni], 0, 0, 0);
  };

  LOAD(0, a0, b0);
  for (int t = 0; t < nt; t += 2) {
    STORE(0, a0, b0);
    __syncthreads();
    LOAD(t + 1, a1, b1);
    COMPUTE(0);
    STORE(1, a1, b1);
    __syncthreads();
    if (t + 2 < nt) LOAD(t + 2, a0, b0);
    COMPUTE(1);
  }
  const int mb = m0 + wr * 64 + ((lane >> 4) << 2);
  const int nb = n0 + wc * 64 + (lane & 15);
#pragma unroll
  for (int ni = 0; ni < 4; ++ni) {
    const int n = nb + ni * 16;
    float s = 1.f, bb_ = 0.f;
    if (EP) { s = g[n] * RSQC; bb_ = bia[n]; }
#pragma unroll
    for (int mi = 0; mi < 4; ++mi)
#pragma unroll
      for (int r = 0; r < 4; ++r) {
        float v = acc[mi][ni][r];
        if (EP) v = fmaxf(v * s + bb_, 0.f);
        out[(size_t)(mb + mi * 16 + r) * N + n] = f2bf(v);
      }
  }
}

// Swapped GEMM body (vT path): out bf16 (b, m, pos); BN per-m.
__device__ __forceinline__ void gemm_swv_body(
    u16* As, u16* Bs,
    const u16* __restrict__ A, const u16* __restrict__ Bt, u16* __restrict__ out,
    const float* __restrict__ g, const float* __restrict__ bia,
    int Mtot, int K, int lda, int ldb, int m0, int n0) {
  const int tid = threadIdx.x, lane = tid & 63, wv = tid >> 6;
  const int wr = wv >> 1, wc = wv & 1;
  const int r0 = lane >> 2, ksl = (lane & 3) * 8;
  const int wofs = (lane >> 2) * 32 + (((lane & 3) ^ ((lane >> 3) & 3)) << 3);
  const int rsl = (((lane >> 4) ^ ((lane >> 1) & 3)) << 3);
  f32x4 acc[4][4] = {};
  const int nt = K >> 5;

  short8 a0[2], b0[2], a1[2], b1[2];
  auto LOAD = [&](int t, short8 av[2], short8 bv[2]) {
    const int k0 = t << 5;
#pragma unroll
    for (int i = 0; i < 2; ++i) {
      const int row = (wv * 2 + i) * 16 + r0;
      av[i] = *(const short8*)(A + (size_t)(m0 + row) * lda + k0 + ksl);
      bv[i] = *(const short8*)(Bt + (size_t)(n0 + row) * ldb + k0 + ksl);
    }
  };
  auto STORE = [&](int buf, short8 av[2], short8 bv[2]) {
#pragma unroll
    for (int i = 0; i < 2; ++i) {
      const int o = buf * 4096 + (wv * 2 + i) * 512 + wofs;
      *(short8*)&As[o] = av[i];
      *(short8*)&Bs[o] = bv[i];
    }
  };
  auto COMPUTE = [&](int buf) {
    short8 a[4], b[4];
#pragma unroll
    for (int mi = 0; mi < 4; ++mi)
      a[mi] = *(const short8*)&As[buf * 4096 + (wr * 4 + mi) * 512 + (lane & 15) * 32 + rsl];
#pragma unroll
    for (int ni = 0; ni < 4; ++ni)
      b[ni] = *(const short8*)&Bs[buf * 4096 + (wc * 4 + ni) * 512 + (lane & 15) * 32 + rsl];
#pragma unroll
    for (int mi = 0; mi < 4; ++mi)
#pragma unroll
      for (int ni = 0; ni < 4; ++ni)
        acc[mi][ni] = __builtin_amdgcn_mfma_f32_16x16x32_bf16(a[mi], b[ni], acc[mi][ni], 0, 0, 0);
  };

  LOAD(0, a0, b0);
  for (int t = 0; t < nt; t += 2) {
    STORE(0, a0, b0);
    __syncthreads();
    LOAD(t + 1, a1, b1);
    COMPUTE(0);
    STORE(1, a1, b1);
    __syncthreads();
    if (t + 2 < nt) LOAD(t + 2, a0, b0);
    COMPUTE(1);
  }
  const int mb = m0 + wr * 64 + ((lane >> 4) << 2);
  const int nb = n0 + wc * 64 + (lane & 15);
#pragma unroll
  for (int mi = 0; mi < 4; ++mi)
#pragma unroll
    for (int r = 0; r < 4; ++r) {
      const int m = mb + mi * 16 + r;
      const float s = g[m] * RSQC, bb_ = bia[m];
#pragma unroll
      for (int ni = 0; ni < 4; ++ni) {
        const int n = nb + ni * 16;
        out[((size_t)(n >> 12) * Mtot + m) * 4096 + (n & 4095)] =
            f2bf(fmaxf(acc[mi][ni][r] * s + bb_, 0.f));
      }
    }
}

// standalone 128x128 GEMM kernel (selout path)
template <bool EP>
__global__ __launch_bounds__(256) void gemm_std(
    const u16* __restrict__ A, const u16* __restrict__ Bt, u16* __restrict__ out,
    const float* __restrict__ g, const float* __restrict__ bia,
    int N, int K, int lda, int ldb) {
  __shared__ __attribute__((aligned(16))) u16 As[2 * 4096];
  __shared__ __attribute__((aligned(16))) u16 Bs[2 * 4096];
  gemm_std_body<EP>(As, Bs, A, Bt, out, g, bia, N, K, lda, ldb,
                    blockIdx.y * 128, blockIdx.x * 128);
}

// fused mini: blocks 0-3 KD = kw1c@D^T, 4-7 VD = vwc@D^T  (256x256, K=768)
__global__ __launch_bounds__(256) void gemm_mini(
    const u16* __restrict__ kw1c, const u16* __restrict__ vwc,
    const u16* __restrict__ D, u16* __restrict__ KD, u16* __restrict__ VD) {
  __shared__ __attribute__((aligned(16))) u16 As[2 * 4096];
  __shared__ __attribute__((aligned(16))) u16 Bs[2 * 4096];
  int id = blockIdx.x;
  if (id < 4)
    gemm_std_body<false>(As, Bs, kw1c, D, KD, nullptr, nullptr, 256, 768, 768, 768,
                         (id >> 1) * 128, (id & 1) * 128);
  else {
    id -= 4;
    gemm_std_body<false>(As, Bs, vwc, D, VD, nullptr, nullptr, 256, 768, 768, 768,
                         (id >> 1) * 128, (id & 1) * 128);
  }
}

// fused stage-1: blocks 0-255 q1 | 256-511 k1 | 512-767 vT  (independent GEMMs)
__global__ __launch_bounds__(256) void gemm_qkv(
    const u16* __restrict__ featsT, const u16* __restrict__ qw1c, u16* __restrict__ q1,
    const float* __restrict__ qg1, const float* __restrict__ qb1,
    const u16* __restrict__ wcls, const u16* __restrict__ KD, u16* __restrict__ k1,
    const float* __restrict__ kg1, const float* __restrict__ kb1,
    const u16* __restrict__ VD, u16* __restrict__ vT,
    const float* __restrict__ vg, const float* __restrict__ vb) {
  __shared__ __attribute__((aligned(16))) u16 As[2 * 4096];
  __shared__ __attribute__((aligned(16))) u16 Bs[2 * 4096];
  int id = blockIdx.x;
  if (id < 256) {
    gemm_std_body<true>(As, Bs, featsT, qw1c, q1, qg1, qb1, 256, 768, 768, 768,
                        (id >> 1) * 128, (id & 1) * 128);
  } else if (id < 512) {
    id -= 256;
    gemm_std_body<true>(As, Bs, wcls, KD, k1, kg1, kb1, 256, 256, 256, 256,
                        (id >> 1) * 128, (id & 1) * 128);
  } else {
    id -= 512;
    gemm_swv_body(As, Bs, VD, wcls, vT, vg, vb, 256, 256, 256, 256,
                  (id >> 7) * 128, (id & 127) * 128);
  }
}

// fused stage-2: blocks 0-255 qbuf | 256-511 kbuf
__global__ __launch_bounds__(256) void gemm_qk2(
    const u16* __restrict__ q1, const u16* __restrict__ qw2c, u16* __restrict__ qbuf,
    const float* __restrict__ qg2, const float* __restrict__ qb2,
    const u16* __restrict__ k1, const u16* __restrict__ kw2c, u16* __restrict__ kbuf,
    const float* __restrict__ kg2, const float* __restrict__ kb2) {
  __shared__ __attribute__((aligned(16))) u16 As[2 * 4096];
  __shared__ __attribute__((aligned(16))) u16 Bs[2 * 4096];
  int id = blockIdx.x;
  if (id < 256) {
    gemm_std_body<true>(As, Bs, q1, qw2c, qbuf, qg2, qb2, 256, 256, 256, 256,
                        (id >> 1) * 128, (id & 1) * 128);
  } else {
    id -= 256;
    gemm_std_body<true>(As, Bs, k1, kw2c, kbuf, kg2, kb2, 256, 256, 256, 256,
                        (id >> 1) * 128, (id & 1) * 128);
  }
}

// ---------------- implicit 3x3 conv, 128-row blocks (R15-proven) ----------------
// MODE 1: store raw f32; MODE 2: in-place +BN+relu.
template <int MODE>
__global__ __launch_bounds__(256) void conv_frag(
    const u16* __restrict__ Af, const u16* __restrict__ X, float* out,
    const float* __restrict__ g, const float* __restrict__ bia) {
  __shared__ __attribute__((aligned(16))) u16 Hb[2][264 * 32];
  const int tid = threadIdx.x, lane = tid & 63, wv = tid >> 6;
  const int wr = wv >> 1, wc = wv & 1;
  const int id = blockIdx.y * 128 + blockIdx.x;
  const int xcd = id & 7, sl = id >> 3;
  const int m0 = (sl % 6) * 128;
  const int n0 = (xcd * 16 + sl / 6) * 128;
  f32x4 acc[4][4] = {};

  int vmask[4];
#pragma unroll
  for (int i = 0; i < 4; ++i) {
    const int hw = (n0 + wc * 64 + i * 16 + (lane & 15)) & 4095;
    const int h = hw >> 6, w = hw & 63;
    int m = 0;
#pragma unroll
    for (int t = 0; t < 9; ++t)
      if ((unsigned)(h + t / 3 - 1) < 64u && (unsigned)(w + t % 3 - 1) < 64u) m |= 1 << t;
    vmask[i] = m;
  }

  const int fb = (m0 >> 4) + wr * 4;
  auto aload = [&](int kc, int tap, short8 d[4]) {
    const u16* base = Af + ((size_t)((kc * 9 + tap) * 48 + fb) << 9) + lane * 8;
#pragma unroll
    for (int mi = 0; mi < 4; ++mi) d[mi] = *(const short8*)(base + (mi << 9));
  };
  auto hstage = [&](int kc, int buf) {
#pragma unroll
    for (int j = 0; j < 5; ++j) {
      const int cid = tid + j * 256;
      if (cid < 1032) {
        int q = n0 - 65 + (cid >> 2);
        q = q < 0 ? 0 : (q > 16383 ? 16383 : q);  // clamped rows only used masked
        const int row = cid >> 2;
        const int s = (cid & 3) ^ ((row >> 1) & 3);
        gload16(X + (size_t)q * 768 + kc * 32 + s * 8, &Hb[buf][(size_t)cid * 8]);
      }
    }
  };

  hstage(0, 0);
  short8 acur[4], anxt[4];
  aload(0, 0, acur);
  __syncthreads();
  int p = 0;
  for (int kc = 0; kc < 24; ++kc) {
    if (kc < 23) hstage(kc + 1, p ^ 1);
#pragma unroll
    for (int tap = 0; tap < 9; ++tap) {
      const int nk = (tap == 8) ? (kc == 23 ? 23 : kc + 1) : kc;
      const int ntp = (tap == 8) ? 0 : tap + 1;
      aload(nk, ntp, anxt);
      const int shift = (tap / 3 - 1) * 64 + (tap % 3 - 1);
#pragma unroll
      for (int ni = 0; ni < 4; ++ni) {
        const int hrow = wc * 64 + ni * 16 + (lane & 15) + 65 + shift;
        short8 bv = *(const short8*)((const char*)&Hb[p][0] + hrow * 64 +
                                     (((lane >> 4) ^ ((hrow >> 1) & 3)) << 4));
        short8 z = {};
        if (!((vmask[ni] >> tap) & 1)) bv = z;
#pragma unroll
        for (int mi = 0; mi < 4; ++mi)
          acc[mi][ni] = __builtin_amdgcn_mfma_f32_16x16x32_bf16(acur[mi], bv, acc[mi][ni], 0, 0, 0);
      }
#pragma unroll
      for (int mi = 0; mi < 4; ++mi) acur[mi] = anxt[mi];
    }
    if (kc < 23) {
      __syncthreads();
      p ^= 1;
    }
  }
  const int mb = m0 + wr * 64 + ((lane >> 4) << 2);
  const int nb = n0 + wc * 64 + (lane & 15);
#pragma unroll
  for (int mi = 0; mi < 4; ++mi)
#pragma unroll
    for (int r = 0; r < 4; ++r) {
      const int m = mb + mi * 16 + r;
      float s = 0.f, bb_ = 0.f;
      if (MODE == 2) { s = g[m] * RSQC; bb_ = bia[m]; }
#pragma unroll
      for (int ni = 0; ni < 4; ++ni) {
        const int n = nb + ni * 16;
        const size_t oidx = ((size_t)(n >> 12) * 768 + m) * 4096 + (n & 4095);
        if (MODE == 1) out[oidx] = acc[mi][ni][r];
        else out[oidx] = fmaxf((acc[mi][ni][r] + out[oidx]) * s + bb_, 0.f);
      }
    }
}

// ---------------- 64-row m-tile variant, 1536 blocks (conv pass 2) ----------------
__global__ __launch_bounds__(256) void conv_ms(
    const u16* __restrict__ Af, const u16* __restrict__ X, float* out,
    const float* __restrict__ g, const float* __restrict__ bia) {
  __shared__ __attribute__((aligned(16))) u16 Hb[2][264 * 32];
  const int tid = threadIdx.x, lane = tid & 63, wv = tid >> 6;
  const int wr = wv >> 1, wc = wv & 1;
  const int id = blockIdx.x;
  const int xcd = id & 7, sl = id >> 3;  // sl 0..191
  const int m0 = (sl % 12) * 64;
  const int n0 = (xcd * 16 + sl / 12) * 128;
  f32x4 acc[2][4] = {};

  int vmask[4];
#pragma unroll
  for (int i = 0; i < 4; ++i) {
    const int hw = (n0 + wc * 64 + i * 16 + (lane & 15)) & 4095;
    const int h = hw >> 6, w = hw & 63;
    int m = 0;
#pragma unroll
    for (int t = 0; t < 9; ++t)
      if ((unsigned)(h + t / 3 - 1) < 64u && (unsigned)(w + t % 3 - 1) < 64u) m |= 1 << t;
    vmask[i] = m;
  }

  const int fb = (m0 >> 4) + wr * 2;
  auto aload = [&](int kc, int tap, short8 d[2]) {
    const u16* base = Af + ((size_t)((kc * 9 + tap) * 48 + fb) << 9) + lane * 8;
#pragma unroll
    for (int mi = 0; mi < 2; ++mi) d[mi] = *(const short8*)(base + (mi << 9));
  };
  auto hstage = [&](int kc, int buf) {
#pragma unroll
    for (int j = 0; j < 5; ++j) {
      const int cid = tid + j * 256;
      if (cid < 1032) {
        int q = n0 - 65 + (cid >> 2);
        q = q < 0 ? 0 : (q > 16383 ? 16383 : q);
        const int row = cid >> 2;
        const int s = (cid & 3) ^ ((row >> 1) & 3);
        gload16(X + (size_t)q * 768 + kc * 32 + s * 8, &Hb[buf][(size_t)cid * 8]);
      }
    }
  };

  hstage(0, 0);
  short8 acur[2], anxt[2];
  aload(0, 0, acur);
  __syncthreads();
  int p = 0;
  for (int kc = 0; kc < 24; ++kc) {
    if (kc < 23) hstage(kc + 1, p ^ 1);
#pragma unroll
    for (int tap = 0; tap < 9; ++tap) {
      const int nk = (tap == 8) ? (kc == 23 ? 23 : kc + 1) : kc;
      const int ntp = (tap == 8) ? 0 : tap + 1;
      aload(nk, ntp, anxt);
      const int shift = (tap / 3 - 1) * 64 + (tap % 3 - 1);
#pragma unroll
      for (int ni = 0; ni < 4; ++ni) {
        const int hrow = wc * 64 + ni * 16 + (lane & 15) + 65 + shift;
        short8 bv = *(const short8*)((const char*)&Hb[p][0] + hrow * 64 +
                                     (((lane >> 4) ^ ((hrow >> 1) & 3)) << 4));
        short8 z = {};
        if (!((vmask[ni] >> tap) & 1)) bv = z;
#pragma unroll
        for (int mi = 0; mi < 2; ++mi)
          acc[mi][ni] = __builtin_amdgcn_mfma_f32_16x16x32_bf16(acur[mi], bv, acc[mi][ni], 0, 0, 0);
      }
#pragma unroll
      for (int mi = 0; mi < 2; ++mi) acur[mi] = anxt[mi];
    }
    if (kc < 23) {
      __syncthreads();
      p ^= 1;
    }
  }
  const int mb = m0 + wr * 32 + ((lane >> 4) << 2);
  const int nb = n0 + wc * 64 + (lane & 15);
#pragma unroll
  for (int mi = 0; mi < 2; ++mi)
#pragma unroll
    for (int r = 0; r < 4; ++r) {
      const int m = mb + mi * 16 + r;
      const float s = g[m] * RSQC, bb_ = bia[m];
#pragma unroll
      for (int ni = 0; ni < 4; ++ni) {
        const int n = nb + ni * 16;
        const size_t oidx = ((size_t)(n >> 12) * 768 + m) * 4096 + (n & 4095);
        out[oidx] = fmaxf((acc[mi][ni][r] + out[oidx]) * s + bb_, 0.f);
      }
    }
}

// ---------------- flash attention (R12-proven: 256 thr, QBLK=64, grid (64,4)) ----
__global__ __launch_bounds__(256) void flash_attn(const u16* Q,
                                                  const u16* __restrict__ Kg,
                                                  const u16* __restrict__ Vt,
                                                  u16* ctx) {
  __shared__ __attribute__((aligned(16))) u16 KVs[64 * 256];
  __shared__ __attribute__((aligned(16))) u16 Ps[4096];
  const int tid = threadIdx.x, lane = tid & 63, wv = tid >> 6;
  const int b = blockIdx.y, q0 = blockIdx.x * 64;
  const u16* qb = Q + ((size_t)b * 4096 + q0) * 256;
  const u16* kb = Kg + (size_t)b * 4096 * 256;
  const u16* vb = Vt + (size_t)b * 256 * 4096;
  const float scale = 0.0625f;

  short8 qf[8];
  {
    const int arow = wv * 16 + (lane & 15);
    const u16* qrow = qb + (size_t)arow * 256 + (lane >> 4) * 8;
#pragma unroll
    for (int kk = 0; kk < 8; ++kk) qf[kk] = *(const short8*)(qrow + kk * 32);
  }
  float mreg[4] = {-1e30f, -1e30f, -1e30f, -1e30f};
  float lsum[4] = {0.f, 0.f, 0.f, 0.f};
  f32x4 o[16] = {};

  for (int t = 0; t < 64; ++t) {
    {
      const int r = tid >> 5, sb = (tid & 31) * 16;
      const char* ksrc = (const char*)(kb + (size_t)t * 64 * 256);
#pragma unroll
      for (int i = 0; i < 8; ++i) {
        int row = i * 8 + r;
        short8 v = *(const short8*)(ksrc + (size_t)row * 512 + sb);
        *(short8*)((char*)KVs + row * 512 + (sb ^ ((row & 7) << 4))) = v;
      }
    }
    __syncthreads();
    f32x4 s4[4] = {};
    __builtin_amdgcn_s_setprio(1);
#pragma unroll
    for (int kk = 0; kk < 8; ++kk) {
      const int cb = (kk * 32 + ((lane >> 4) * 8)) * 2;
#pragma unroll
      for (int ni = 0; ni < 4; ++ni) {
        const int brow = ni * 16 + (lane & 15);
        short8 bb = *(const short8*)((const char*)KVs + brow * 512 + (cb ^ ((brow & 7) << 4)));
        s4[ni] = __builtin_amdgcn_mfma_f32_16x16x32_bf16(qf[kk], bb, s4[ni], 0, 0, 0);
      }
    }
    __builtin_amdgcn_s_setprio(0);
    float al[4], p[4][4];
#pragma unroll
    for (int r = 0; r < 4; ++r) {
      float v0 = fmaxf(fmaxf(s4[0][r], s4[1][r]), fmaxf(s4[2][r], s4[3][r]));
      v0 = fmaxf(v0, __shfl_xor(v0, 1));
      v0 = fmaxf(v0, __shfl_xor(v0, 2));
      v0 = fmaxf(v0, __shfl_xor(v0, 4));
      v0 = fmaxf(v0, __shfl_xor(v0, 8));
      const float mn = fmaxf(mreg[r], v0 * scale);
      al[r] = __expf(mreg[r] - mn);
      mreg[r] = mn;
      float srow = 0.f;
#pragma unroll
      for (int ni = 0; ni < 4; ++ni) {
        float pv = __expf(s4[ni][r] * scale - mn);
        p[ni][r] = pv;
        srow += pv;
      }
      srow += __shfl_xor(srow, 1);
      srow += __shfl_xor(srow, 2);
      srow += __shfl_xor(srow, 4);
      srow += __shfl_xor(srow, 8);
      lsum[r] = lsum[r] * al[r] + srow;
    }
#pragma unroll
    for (int nf = 0; nf < 16; ++nf)
#pragma unroll
      for (int r = 0; r < 4; ++r) o[nf][r] *= al[r];
    {
      char* pbase = (char*)Ps + wv * 2048;
#pragma unroll
      for (int ni = 0; ni < 4; ++ni)
#pragma unroll
        for (int r = 0; r < 4; ++r) {
          const int row = ((lane >> 4) << 2) + r, col = ni * 16 + (lane & 15);
          *(u16*)(pbase + row * 128 + ((col * 2) ^ ((row & 7) << 4))) = f2bf(p[ni][r]);
        }
    }
    __syncthreads();
    {
      const int slot = tid & 7;
#pragma unroll
      for (int i = 0; i < 8; ++i) {
        const int cc = i * 32 + (tid >> 3);
        short8 v = *(const short8*)((const char*)vb + ((size_t)cc * 4096 + t * 64) * 2 + slot * 16);
        *(short8*)((char*)KVs + cc * 128 + ((slot * 16) ^ ((cc & 7) << 4))) = v;
      }
    }
    __syncthreads();
    short8 pa[2];
#pragma unroll
    for (int kk = 0; kk < 2; ++kk) {
      const int row = lane & 15;
      const int cb = (kk * 32 + ((lane >> 4) * 8)) * 2;
      pa[kk] = *(const short8*)((const char*)Ps + wv * 2048 + row * 128 + (cb ^ ((row & 7) << 4)));
    }
    __builtin_amdgcn_s_setprio(1);
#pragma unroll
    for (int nf = 0; nf < 16; ++nf) {
      const int crow = nf * 16 + (lane & 15);
#pragma unroll
      for (int kk = 0; kk < 2; ++kk) {
        const int kb2 = (kk * 32 + ((lane >> 4) * 8)) * 2;
        short8 bb = *(const short8*)((const char*)KVs + crow * 128 + (kb2 ^ ((crow & 7) << 4)));
        o[nf] = __builtin_amdgcn_mfma_f32_16x16x32_bf16(pa[kk], bb, o[nf], 0, 0, 0);
      }
    }
    __builtin_amdgcn_s_setprio(0);
    __syncthreads();
  }
  u16* cb_ = ctx + ((size_t)b * 4096 + q0) * 256;
#pragma unroll
  for (int r = 0; r < 4; ++r) {
    const int row = wv * 16 + ((lane >> 4) << 2) + r;
    const float inv = 1.f / lsum[r];
#pragma unroll
    for (int nf = 0; nf < 16; ++nf) {
      const int col = nf * 16 + (lane & 15);
      cb_[(size_t)row * 256 + col] = f2bf(o[nf][r] * inv);
    }
  }
}

// ---------------- launch ----------------

extern "C" void kernel_launch(void* const* d_in, const int* in_sizes, int n_in,
                              void* d_out, int out_size, void* d_ws, size_t ws_size,
                              hipStream_t stream) {
  (void)in_sizes; (void)n_in; (void)out_size;
  const float* feats  = (const float*)d_in[0];
  const float* preds  = (const float*)d_in[1];
  const float* text   = (const float*)d_in[2];
  const float* memory = (const float*)d_in[3];
  const float* tmem   = (const float*)d_in[4];
  const float* qw1 = (const float*)d_in[5];  const float* qg1 = (const float*)d_in[6];  const float* qb1 = (const float*)d_in[7];
  const float* qw2 = (const float*)d_in[8];  const float* qg2 = (const float*)d_in[9];  const float* qb2 = (const float*)d_in[10];
  const float* kw1 = (const float*)d_in[11]; const float* kg1 = (const float*)d_in[12]; const float* kb1 = (const float*)d_in[13];
  const float* kw2 = (const float*)d_in[14]; const float* kg2 = (const float*)d_in[15]; const float* kb2 = (const float*)d_in[16];
  const float* vw  = (const float*)d_in[17]; const float* vg  = (const float*)d_in[18]; const float* vb  = (const float*)d_in[19];
  const float* ow  = (const float*)d_in[20]; const float* og  = (const float*)d_in[21]; const float* ob  = (const float*)d_in[22];
  const float* bw  = (const float*)d_in[23]; const float* bg  = (const float*)d_in[24]; const float* bb  = (const float*)d_in[25];

  float* dout = (float*)d_out;  // 12,582,912 f32
  char* ws = (char*)d_ws;
  u16* featsT = (u16*)(ws);                           // 25,165,824 B
  u16* selout = (u16*)(ws + 25165824);                // 25,165,824 B
  u16* S2     = (u16*)(ws + 50331648);                //  8,388,608 B (k1)
  u16* qw1c   = (u16*)(ws + 58720256);
  u16* kw1c   = (u16*)(ws + 59113472);
  u16* vwc    = (u16*)(ws + 59506688);
  u16* owc    = (u16*)(ws + 59899904);
  u16* qw2c   = (u16*)(ws + 60293120);
  u16* kw2c   = (u16*)(ws + 60424192);
  u16* w9     = S2;  // spans S2..60,948,480
  const size_t WS_NEED = 60948480;
  // early scratch inside selout (dead before selout gemm writes):
  u16* D   = selout;                                  // 393,216 B
  u16* KD  = (u16*)((char*)selout + 393216);          // 131,072 B
  u16* VD  = (u16*)((char*)selout + 524288);          // 131,072 B
  int* idx = (int*)((char*)selout + 655360);          //   1,024 B
  u16* q1  = (u16*)((char*)selout + 1048576);         // 8,388,608 B (dead before selout write)
  u16* O0 = (u16*)dout;
  u16* O1 = O0 + 4194304;
  u16* O2 = O0 + 8388608;

  if (ws_size < WS_NEED) {
    probe_fill<<<2048, 256, 0, stream>>>(dout, 1000.0f);
    return;
  }

  u16* wcls = O0;
  u16* k1 = S2;
  u16* kbuf = O1, *vT = O2;
  u16* qbuf = O0, *ctx = O0;

  sim_argmax<<<200, 64, 0, stream>>>(text, tmem, idx);
  build_d<<<768, 256, 0, stream>>>(memory, idx, D);
  wcls_kernel<<<256, 256, 0, stream>>>(preds, wcls);
  transpose_feats<<<dim3(64, 12, 4), 256, 0, stream>>>(feats, featsT);
  cast_all<<<3584, 256, 0, stream>>>(qw1, qw1c, kw1, kw1c, vw, vwc, ow, owc, qw2, qw2c, kw2, kw2c);

  // KD/VD fused (8 blocks)
  gemm_mini<<<8, 256, 0, stream>>>(kw1c, vwc, D, KD, VD);
  // q1 | k1 | vT fused (768 blocks = 3/CU)
  gemm_qkv<<<768, 256, 0, stream>>>(featsT, qw1c, q1, qg1, qb1,
                                    wcls, KD, k1, kg1, kb1,
                                    VD, vT, vg, vb);
  // qbuf | kbuf fused (512 blocks) — wcls (O0) dead; qbuf overwrites O0
  gemm_qk2<<<512, 256, 0, stream>>>(q1, qw2c, qbuf, qg2, qb2,
                                    k1, kw2c, kbuf, kg2, kb2);
  // attention: Q=O0, K=O1, V=O2 -> ctx=O0 (self-alias safe)
  flash_attn<<<dim3(64, 4), 256, 0, stream>>>(qbuf, kbuf, vT, ctx);
  // sel_out = cbr(ctx @ ow) -> selout (q1/D/KD/VD dead)
  gemm_std<true><<<dim3(6, 128), 256, 0, stream>>>(ctx, owc, selout, og, ob, 768, 256, 256, 256);
  // conv pass 1 (128-row blocks): feats half -> raw f32 partial
  repack2<<<288, 256, 0, stream>>>(bw, w9, 0);
  conv_frag<1><<<dim3(128, 6), 256, 0, stream>>>(w9, featsT, dout, nullptr, nullptr);
  // conv pass 2 (64-row blocks, 1536 blocks): selout half, +BN+relu
  repack2<<<288, 256, 0, stream>>>(bw, w9, 768);
  conv_ms<<<1536, 256, 0, stream>>>(w9, selout, dout, bg, bb);
}